// Round 6
// baseline (455.519 us; speedup 1.0000x reference)
//
#include <hip/hip_runtime.h>

#define NPTS 4096
#define NQ   1024     // S
#define NB   16       // B
#define KNN  32
#define MROWS 524288  // B*S*K
#define FLT_MAX_ 3.402823466e+38f

typedef __attribute__((ext_vector_type(8))) short short8;
typedef __attribute__((ext_vector_type(4))) float f32x4;

// ---------- bf16 helpers (manual, RNE) ----------
__device__ inline unsigned short f2bf(float x){
  unsigned u = __float_as_uint(x);
  u += 0x7fffu + ((u >> 16) & 1u);
  return (unsigned short)(u >> 16);
}
__device__ inline float bf2f(unsigned v){           // low 16 bits used
  return __uint_as_float(v << 16);
}

// normalize+relu 8 bf16 (one A-fragment k-slice) -> bf16 frag
__device__ inline short8 norm_frag(uint4 v, const float* sc, const float* sh){
  short8 r;
  const unsigned u[4] = {v.x, v.y, v.z, v.w};
  #pragma unroll
  for (int i = 0; i < 8; ++i){
    const unsigned raw = (i & 1) ? (u[i >> 1] >> 16) : (u[i >> 1] & 0xffffu);
    const float f = fmaxf(fmaf(bf2f(raw), sc[i], sh[i]), 0.f);
    r[i] = (short)f2bf(f);
  }
  return r;
}

// sorted-insert of packed key pd into top-4 cache (c0<=c1<=c2<=c3)
__device__ __forceinline__ void ins4(double pd, double& c0, double& c1, double& c2, double& c3){
  const double t3 = fmin(c3, pd);
  const double n2 = fmin(c2, t3), x3 = fmax(c2, t3);
  const double n1 = fmin(c1, n2), x2 = fmax(c1, n2);
  const double n0 = fmin(c0, n1), x1 = fmax(c0, n1);
  c0 = n0; c1 = x1; c2 = x2; c3 = x3;
}

// rescan for ONE query with skip mask (rare path)
__device__ __noinline__ void scan1(const float* xs, const float* ys, const float* zs,
                                   int lane, float qx, float qy, float qz, float src2,
                                   unsigned long long skip,
                                   double& c0, double& c1, double& c2, double& c3){
  for (int e = 0; e < 64; ++e){
    if ((skip >> e) & 1ull) continue;
    const int j = (e << 6) | lane;
    const float px = xs[j], py = ys[j], pz = zs[j];
    const float dst2 = (px*px + py*py) + pz*pz;
    const float dot  = (qx*px + qy*py) + qz*pz;
    const float d = fmaf(dot, -2.f, src2 + dst2);
    const unsigned long long uu =
        (unsigned long long)__double_as_longlong((double)d) | (unsigned)j;
    ins4(__longlong_as_double((long long)uu), c0, c1, c2, c3);
  }
}

// ---------- Kernel 1: top-K=32 NN, TWO queries per wave (interleaved chains) ----------
// key = as_double(d) | j (low 12 mantissa bits; exact order (d, j)).
// Block 0 also zeroes the stats accumulators (512 floats).
__global__ __launch_bounds__(512) void topk_kernel(const float* __restrict__ xyz,
                                                   int* __restrict__ idx_out,
                                                   float* __restrict__ statsacc){
  __shared__ float xs[NPTS], ys[NPTS], zs[NPTS];   // 48 KB
  const int tid = threadIdx.x;
  if (blockIdx.x == 0 && tid < 512) statsacc[tid] = 0.f;

  const int b = blockIdx.x >> 6;         // 64 blocks per batch, 16 queries/block
  const float* xb = xyz + (size_t)b * NPTS * 3;
  for (int p = tid; p < NPTS; p += 512){
    xs[p] = xb[3*p + 0];
    ys[p] = xb[3*p + 1];
    zs[p] = xb[3*p + 2];
  }
  __syncthreads();

  const int wv   = tid >> 6;
  const int lane = tid & 63;
  const int qA   = blockIdx.x * 16 + wv*2;    // two queries per wave
  const int qB   = qA + 1;
  const int sA_  = qA & (NQ - 1);
  const int sB_  = qB & (NQ - 1);

  const float axq = xs[sA_], ayq = ys[sA_], azq = zs[sA_];
  const float bxq = xs[sB_], byq = ys[sB_], bzq = zs[sB_];
  const float src2A = (axq*axq + ayq*ayq) + azq*azq;
  const float src2B = (bxq*bxq + byq*byq) + bzq*bzq;

  const double DINF = __builtin_inf();
  double a0 = DINF, a1 = DINF, a2 = DINF, a3 = DINF;
  double b0 = DINF, b1 = DINF, b2 = DINF, b3 = DINF;

  // init scan: shared point loads, dual independent insert chains
  for (int e = 0; e < 64; ++e){
    const int j = (e << 6) | lane;
    const float px = xs[j], py = ys[j], pz = zs[j];
    const float dst2 = (px*px + py*py) + pz*pz;
    const float dotA = (axq*px + ayq*py) + azq*pz;
    const float dotB = (bxq*px + byq*py) + bzq*pz;
    const float dA = fmaf(dotA, -2.f, src2A + dst2);
    const float dB = fmaf(dotB, -2.f, src2B + dst2);
    const unsigned long long uA =
        (unsigned long long)__double_as_longlong((double)dA) | (unsigned)j;
    const unsigned long long uB =
        (unsigned long long)__double_as_longlong((double)dB) | (unsigned)j;
    ins4(__longlong_as_double((long long)uA), a0, a1, a2, a3);
    ins4(__longlong_as_double((long long)uB), b0, b1, b2, b3);
  }

  unsigned long long skipA = 0ull, skipB = 0ull;
  int ncA = 4, ncB = 4;
  int winA = 0, winB = 0;

  #pragma unroll 1
  for (int it = 0; it < KNN; ++it){
    double wA = a0, wB = b0;
    #pragma unroll
    for (int m = 32; m >= 1; m >>= 1){
      wA = fmin(wA, __shfl_xor(wA, m, 64));
      wB = fmin(wB, __shfl_xor(wB, m, 64));
    }
    if (lane == it){
      winA = (int)((unsigned)__double_as_longlong(wA) & 0xFFFu);
      winB = (int)((unsigned)__double_as_longlong(wB) & 0xFFFu);
    }
    if (a0 == wA){                  // unique keys -> exactly one lane
      const unsigned lo = (unsigned)__double_as_longlong(a0);
      skipA |= 1ull << ((lo >> 6) & 63u);
      a0 = a1; a1 = a2; a2 = a3; a3 = DINF;
      if (--ncA == 0){
        a0 = a1 = a2 = a3 = DINF;
        scan1(xs, ys, zs, lane, axq, ayq, azq, src2A, skipA, a0, a1, a2, a3);
        ncA = 4;
      }
    }
    if (b0 == wB){
      const unsigned lo = (unsigned)__double_as_longlong(b0);
      skipB |= 1ull << ((lo >> 6) & 63u);
      b0 = b1; b1 = b2; b2 = b3; b3 = DINF;
      if (--ncB == 0){
        b0 = b1 = b2 = b3 = DINF;
        scan1(xs, ys, zs, lane, bxq, byq, bzq, src2B, skipB, b0, b1, b2, b3);
        ncB = 4;
      }
    }
  }
  if (lane < KNN){
    idx_out[qA * KNN + lane] = winA;
    idx_out[qB * KNN + lane] = winB;
  }
}

// ---------- Layer 0: gather + concat + MFMA GEMM (K padded 67->96), fused stats ----------
__global__ __launch_bounds__(256) void l0_mfma(const float* __restrict__ xyz,
                                               const float* __restrict__ pts,
                                               const int*   __restrict__ idxbuf,
                                               const float* __restrict__ W,     // (64,67)
                                               const float* __restrict__ bias,  // (64)
                                               unsigned short* __restrict__ hout,
                                               float* __restrict__ acc){
  __shared__ short lds[256*104];
  __shared__ float sacc[128];
  const int tid = threadIdx.x;
  if (tid < 128) sacc[tid] = 0.f;
  const int lane = tid & 63, wv = tid >> 6;
  const int m16 = lane & 15, kg = lane >> 4;

  short8 Bf[4][3];
  float  bl[4];
  for (int ocb = 0; ocb < 4; ++ocb){
    const int n = ocb*16 + m16;
    bl[ocb] = bias[n];
    for (int ks = 0; ks < 3; ++ks){
      short8 t;
      #pragma unroll
      for (int i = 0; i < 8; ++i){
        const int k = ks*32 + kg*8 + i;
        float wv_ = 0.f;
        if (k < 64) wv_ = W[n*67 + 3 + k];
        else if (k < 67) wv_ = W[n*67 + (k - 64)];
        t[i] = (short)f2bf(wv_);
      }
      Bf[ocb][ks] = t;
    }
  }

  {
    const int row = blockIdx.x*256 + tid;
    const int rowq = row >> 5;
    const int b = rowq >> 10, s = rowq & 1023;
    const int j = idxbuf[row];
    const float4* p4 = (const float4*)(pts + ((size_t)b*NPTS + j)*64);
    short* myrow = lds + tid*104;
    #pragma unroll
    for (int u = 0; u < 8; ++u){
      float4 x = p4[2*u], y = p4[2*u+1];
      short8 o;
      o[0]=(short)f2bf(x.x); o[1]=(short)f2bf(x.y); o[2]=(short)f2bf(x.z); o[3]=(short)f2bf(x.w);
      o[4]=(short)f2bf(y.x); o[5]=(short)f2bf(y.y); o[6]=(short)f2bf(y.z); o[7]=(short)f2bf(y.w);
      *(short8*)(myrow + u*8) = o;
    }
    const float* pj = xyz + ((size_t)b*NPTS + j)*3;
    const float* ps = xyz + ((size_t)b*NPTS + s)*3;
    short8 z = 0;
    z[0] = (short)f2bf(pj[0]-ps[0]);
    z[1] = (short)f2bf(pj[1]-ps[1]);
    z[2] = (short)f2bf(pj[2]-ps[2]);
    *(short8*)(myrow + 64) = z;
    short8 zz = 0;
    *(short8*)(myrow + 72) = zz;
    *(short8*)(myrow + 80) = zz;
    *(short8*)(myrow + 88) = zz;
  }
  __syncthreads();

  float sA[4] = {0,0,0,0}, qA[4] = {0,0,0,0};
  const int rowbase = blockIdx.x*256 + wv*64;
  for (int rt = 0; rt < 4; ++rt){
    const short* ar = lds + (wv*64 + rt*16 + m16)*104;
    short8 a0 = *(const short8*)(ar + kg*8);
    short8 a1 = *(const short8*)(ar + 32 + kg*8);
    short8 a2 = *(const short8*)(ar + 64 + kg*8);
    #pragma unroll
    for (int ocb = 0; ocb < 4; ++ocb){
      f32x4 c = {bl[ocb], bl[ocb], bl[ocb], bl[ocb]};
      c = __builtin_amdgcn_mfma_f32_16x16x32_bf16(a0, Bf[ocb][0], c, 0, 0, 0);
      c = __builtin_amdgcn_mfma_f32_16x16x32_bf16(a1, Bf[ocb][1], c, 0, 0, 0);
      c = __builtin_amdgcn_mfma_f32_16x16x32_bf16(a2, Bf[ocb][2], c, 0, 0, 0);
      #pragma unroll
      for (int r = 0; r < 4; ++r){
        const float hv = c[r];
        sA[ocb] += hv; qA[ocb] += hv*hv;
        const int orow = rowbase + rt*16 + kg*4 + r;
        hout[(size_t)orow*64 + ocb*16 + m16] = f2bf(hv);
      }
    }
  }
  #pragma unroll
  for (int ocb = 0; ocb < 4; ++ocb){
    float s = sA[ocb], q = qA[ocb];
    s += __shfl_xor(s, 16, 64); s += __shfl_xor(s, 32, 64);
    q += __shfl_xor(q, 16, 64); q += __shfl_xor(q, 32, 64);
    if (kg == 0){
      atomicAdd(&sacc[ocb*16 + m16], s);
      atomicAdd(&sacc[64 + ocb*16 + m16], q);
    }
  }
  __syncthreads();
  if (tid < 128) atomicAdd(&acc[tid], sacc[tid]);
}

// ---------- Layer 1: in-kernel ss0 + norm+relu(A) + MFMA GEMM 64->64, fused stats ----------
__global__ __launch_bounds__(256) void l1_mfma(const unsigned* __restrict__ hin,
                                               const float* __restrict__ acc0,  // (128) sum|sumsq
                                               const float* __restrict__ g,
                                               const float* __restrict__ be,
                                               const float* __restrict__ W,     // (64,64)
                                               const float* __restrict__ bias,  // (64)
                                               unsigned short* __restrict__ hout,
                                               float* __restrict__ acc1){
  __shared__ float ssl[128];
  __shared__ float sacc[128];
  const int tid = threadIdx.x;
  if (tid < 128) sacc[tid] = 0.f;
  if (tid < 64){
    const float invM = 1.f / (float)MROWS;
    const float mean = acc0[tid] * invM;
    const float var  = acc0[64 + tid] * invM - mean*mean;
    const float scale = g[tid] * rsqrtf(var + 1e-5f);
    ssl[2*tid + 0] = scale;
    ssl[2*tid + 1] = be[tid] - mean * scale;
  }
  __syncthreads();

  const int lane = tid & 63, wv = tid >> 6;
  const int m16 = lane & 15, kg = lane >> 4;

  float scl[2][8], shf[2][8];
  #pragma unroll
  for (int s2 = 0; s2 < 2; ++s2)
    #pragma unroll
    for (int i = 0; i < 8; ++i){
      const int c = s2*32 + kg*8 + i;
      scl[s2][i] = ssl[2*c];
      shf[s2][i] = ssl[2*c + 1];
    }

  short8 Bf[4][2];
  float  bl[4];
  for (int ocb = 0; ocb < 4; ++ocb){
    const int n = ocb*16 + m16;
    bl[ocb] = bias[n];
    #pragma unroll
    for (int s2 = 0; s2 < 2; ++s2){
      short8 t;
      #pragma unroll
      for (int i = 0; i < 8; ++i)
        t[i] = (short)f2bf(W[n*64 + s2*32 + kg*8 + i]);
      Bf[ocb][s2] = t;
    }
  }

  float sA[4] = {0,0,0,0}, qA[4] = {0,0,0,0};
  const int rowbase = blockIdx.x*256 + wv*64;
  for (int rt = 0; rt < 4; ++rt){
    const int arow = rowbase + rt*16 + m16;
    const uint4* pr = (const uint4*)hin + (size_t)arow*8;
    uint4 v0 = pr[kg];
    uint4 v1 = pr[4 + kg];
    short8 a0 = norm_frag(v0, scl[0], shf[0]);
    short8 a1 = norm_frag(v1, scl[1], shf[1]);
    #pragma unroll
    for (int ocb = 0; ocb < 4; ++ocb){
      f32x4 c = {bl[ocb], bl[ocb], bl[ocb], bl[ocb]};
      c = __builtin_amdgcn_mfma_f32_16x16x32_bf16(a0, Bf[ocb][0], c, 0, 0, 0);
      c = __builtin_amdgcn_mfma_f32_16x16x32_bf16(a1, Bf[ocb][1], c, 0, 0, 0);
      #pragma unroll
      for (int r = 0; r < 4; ++r){
        const float hv = c[r];
        sA[ocb] += hv; qA[ocb] += hv*hv;
        const int orow = rowbase + rt*16 + kg*4 + r;
        hout[(size_t)orow*64 + ocb*16 + m16] = f2bf(hv);
      }
    }
  }
  #pragma unroll
  for (int ocb = 0; ocb < 4; ++ocb){
    float s = sA[ocb], q = qA[ocb];
    s += __shfl_xor(s, 16, 64); s += __shfl_xor(s, 32, 64);
    q += __shfl_xor(q, 16, 64); q += __shfl_xor(q, 32, 64);
    if (kg == 0){
      atomicAdd(&sacc[ocb*16 + m16], s);
      atomicAdd(&sacc[64 + ocb*16 + m16], q);
    }
  }
  __syncthreads();
  if (tid < 128) atomicAdd(&acc1[tid], sacc[tid]);
}

// ---------- Layer 2 FUSED: in-kernel ss1 + GEMM 64->128 + stats + per-(q,c) max/min ----------
__global__ __launch_bounds__(256) void l2_fused(const unsigned* __restrict__ hin,
                                                const float* __restrict__ acc1,  // (128)
                                                const float* __restrict__ g,
                                                const float* __restrict__ be,
                                                const float* __restrict__ W,     // (128,64)
                                                const float* __restrict__ bias,  // (128)
                                                float* __restrict__ maxb,        // (16384,128)
                                                float* __restrict__ minb,        // (16384,128)
                                                float* __restrict__ acc2){
  __shared__ float ssl[128];
  __shared__ float sacc[256];
  const int tid = threadIdx.x;
  sacc[tid] = 0.f;
  if (tid < 64){
    const float invM = 1.f / (float)MROWS;
    const float mean = acc1[tid] * invM;
    const float var  = acc1[64 + tid] * invM - mean*mean;
    const float scale = g[tid] * rsqrtf(var + 1e-5f);
    ssl[2*tid + 0] = scale;
    ssl[2*tid + 1] = be[tid] - mean * scale;
  }
  __syncthreads();

  const int lane = tid & 63, wv = tid >> 6;
  const int m16 = lane & 15, kg = lane >> 4;

  float scl[2][8], shf[2][8];
  #pragma unroll
  for (int s2 = 0; s2 < 2; ++s2)
    #pragma unroll
    for (int i = 0; i < 8; ++i){
      const int c = s2*32 + kg*8 + i;
      scl[s2][i] = ssl[2*c];
      shf[s2][i] = ssl[2*c + 1];
    }

  short8 Bf[8][2];
  float  bl[8];
  for (int ocb = 0; ocb < 8; ++ocb){
    const int n = ocb*16 + m16;
    bl[ocb] = bias[n];
    #pragma unroll
    for (int s2 = 0; s2 < 2; ++s2){
      short8 t;
      #pragma unroll
      for (int i = 0; i < 8; ++i)
        t[i] = (short)f2bf(W[n*64 + s2*32 + kg*8 + i]);
      Bf[ocb][s2] = t;
    }
  }

  float sA[8], qA[8];
  float mx[2][8], mn[2][8];
  #pragma unroll
  for (int o = 0; o < 8; ++o){
    sA[o] = 0.f; qA[o] = 0.f;
    mx[0][o] = -FLT_MAX_; mx[1][o] = -FLT_MAX_;
    mn[0][o] =  FLT_MAX_; mn[1][o] =  FLT_MAX_;
  }

  const int rowbase = blockIdx.x*256 + wv*64;   // 2 queries per wave
  #pragma unroll
  for (int rt = 0; rt < 4; ++rt){
    const int qs = rt >> 1;
    const int arow = rowbase + rt*16 + m16;
    const uint4* pr = (const uint4*)hin + (size_t)arow*8;
    uint4 v0 = pr[kg];
    uint4 v1 = pr[4 + kg];
    short8 a0 = norm_frag(v0, scl[0], shf[0]);
    short8 a1 = norm_frag(v1, scl[1], shf[1]);
    #pragma unroll
    for (int ocb = 0; ocb < 8; ++ocb){
      f32x4 c = {bl[ocb], bl[ocb], bl[ocb], bl[ocb]};
      c = __builtin_amdgcn_mfma_f32_16x16x32_bf16(a0, Bf[ocb][0], c, 0, 0, 0);
      c = __builtin_amdgcn_mfma_f32_16x16x32_bf16(a1, Bf[ocb][1], c, 0, 0, 0);
      #pragma unroll
      for (int r = 0; r < 4; ++r){
        const float hv = c[r];
        sA[ocb] += hv; qA[ocb] += hv*hv;
        mx[qs][ocb] = fmaxf(mx[qs][ocb], hv);
        mn[qs][ocb] = fminf(mn[qs][ocb], hv);
      }
    }
  }

  #pragma unroll
  for (int ocb = 0; ocb < 8; ++ocb){
    float s = sA[ocb], q = qA[ocb];
    s += __shfl_xor(s, 16, 64); s += __shfl_xor(s, 32, 64);
    q += __shfl_xor(q, 16, 64); q += __shfl_xor(q, 32, 64);
    if (kg == 0){
      atomicAdd(&sacc[ocb*16 + m16], s);
      atomicAdd(&sacc[128 + ocb*16 + m16], q);
    }
  }

  const int qa = rowbase >> 5;
  #pragma unroll
  for (int qs = 0; qs < 2; ++qs)
    #pragma unroll
    for (int ocb = 0; ocb < 8; ++ocb){
      float a = mx[qs][ocb], b = mn[qs][ocb];
      a = fmaxf(a, __shfl_xor(a, 16, 64)); a = fmaxf(a, __shfl_xor(a, 32, 64));
      b = fminf(b, __shfl_xor(b, 16, 64)); b = fminf(b, __shfl_xor(b, 32, 64));
      if (kg == 0){
        maxb[(size_t)(qa + qs)*128 + ocb*16 + m16] = a;
        minb[(size_t)(qa + qs)*128 + ocb*16 + m16] = b;
      }
    }

  __syncthreads();
  atomicAdd(&acc2[tid], sacc[tid]);
}

// ---------- Final: in-kernel ss2; out = relu(scale*(scale>=0?max:min)+shift); new_xyz ----------
__global__ __launch_bounds__(256) void final_kernel(const float* __restrict__ xyz,
                                                    const float* __restrict__ maxb,
                                                    const float* __restrict__ minb,
                                                    const float* __restrict__ acc2, // (256)
                                                    const float* __restrict__ g,
                                                    const float* __restrict__ be,
                                                    float* __restrict__ out){
  __shared__ float ssl[256];
  const int tid = threadIdx.x;
  if (tid < 128){
    const float invM = 1.f / (float)MROWS;
    const float mean = acc2[tid] * invM;
    const float var  = acc2[128 + tid] * invM - mean*mean;
    const float scale = g[tid] * rsqrtf(var + 1e-5f);
    ssl[2*tid + 0] = scale;
    ssl[2*tid + 1] = be[tid] - mean * scale;
  }
  __syncthreads();

  const int q = blockIdx.x * 4 + (tid >> 6);
  const int p = tid & 63;          // channel pair 0..63 (128 channels)
  const float sc0 = ssl[4*p + 0], sh0 = ssl[4*p + 1];
  const float sc1 = ssl[4*p + 2], sh1 = ssl[4*p + 3];
  const float2 mxv = ((const float2*)(maxb + (size_t)q*128))[p];
  const float2 mnv = ((const float2*)(minb + (size_t)q*128))[p];
  const float h0v = (sc0 >= 0.f) ? mxv.x : mnv.x;
  const float h1v = (sc1 >= 0.f) ? mxv.y : mnv.y;
  float2 r;
  r.x = fmaxf(fmaf(sc0, h0v, sh0), 0.f);
  r.y = fmaxf(fmaf(sc1, h1v, sh1), 0.f);
  ((float2*)(out + (size_t)NB*NQ*3))[(size_t)q*64 + p] = r;
  if (p < 3){
    const int b_ = q >> 10, s = q & 1023;
    out[(size_t)q*3 + p] = xyz[((size_t)b_ * NPTS + s)*3 + p];
  }
}

// ---------- host ----------
extern "C" void kernel_launch(void* const* d_in, const int* in_sizes, int n_in,
                              void* d_out, int out_size, void* d_ws, size_t ws_size,
                              hipStream_t stream){
  (void)in_sizes; (void)n_in; (void)out_size; (void)ws_size;
  const float* xyz = (const float*)d_in[0];
  const float* pts = (const float*)d_in[1];
  const float* W0  = (const float*)d_in[2];
  const float* b0  = (const float*)d_in[3];
  const float* g0  = (const float*)d_in[4];
  const float* be0 = (const float*)d_in[5];
  const float* W1  = (const float*)d_in[6];
  const float* b1  = (const float*)d_in[7];
  const float* g1  = (const float*)d_in[8];
  const float* be1 = (const float*)d_in[9];
  const float* W2  = (const float*)d_in[10];
  const float* b2  = (const float*)d_in[11];
  const float* g2  = (const float*)d_in[12];
  const float* be2 = (const float*)d_in[13];

  // workspace: idx 2MB | acc 512f | h0 64MB | h1 64MB  (~130 MB)
  // max/min buffers (8MB each) reuse the h0 region (dead after l1).
  char* ws = (char*)d_ws;
  int*   idx = (int*)ws;
  float* acc = (float*)(ws + 2097152);
  unsigned* h0 = (unsigned*)(ws + 2101248);
  unsigned* h1 = (unsigned*)(ws + 2101248 + 67108864);
  float* maxb = (float*)h0;
  float* minb = maxb + (size_t)16384*128;
  float* out = (float*)d_out;

  float* acc0 = acc, *acc1 = acc + 128, *acc2 = acc + 256;   // acc2: 256 floats

  topk_kernel<<<1024, 512, 0, stream>>>(xyz, idx, acc);
  l0_mfma<<<2048, 256, 0, stream>>>(xyz, pts, idx, W0, b0, (unsigned short*)h0, acc0);
  l1_mfma<<<2048, 256, 0, stream>>>(h0, acc0, g0, be0, W1, b1, (unsigned short*)h1, acc1);
  l2_fused<<<2048, 256, 0, stream>>>(h1, acc1, g1, be1, W2, b2, maxb, minb, acc2);
  final_kernel<<<4096, 256, 0, stream>>>(xyz, maxb, minb, acc2, g2, be2, out);
}

// Round 7
// 334.498 us; speedup vs baseline: 1.3618x; 1.3618x over previous
//
#include <hip/hip_runtime.h>

#define NPTS 4096
#define NQ   1024     // S
#define NB   16       // B
#define KNN  32
#define MROWS 524288  // B*S*K
#define FLT_MAX_ 3.402823466e+38f

typedef __attribute__((ext_vector_type(8))) short short8;
typedef __attribute__((ext_vector_type(4))) float f32x4;

// ---------- bf16 helpers (manual, RNE) ----------
__device__ inline unsigned short f2bf(float x){
  unsigned u = __float_as_uint(x);
  u += 0x7fffu + ((u >> 16) & 1u);
  return (unsigned short)(u >> 16);
}
__device__ inline float bf2f(unsigned v){           // low 16 bits used
  return __uint_as_float(v << 16);
}

// normalize+relu 8 bf16 (one A-fragment k-slice) -> bf16 frag
__device__ inline short8 norm_frag(uint4 v, const float* sc, const float* sh){
  short8 r;
  const unsigned u[4] = {v.x, v.y, v.z, v.w};
  #pragma unroll
  for (int i = 0; i < 8; ++i){
    const unsigned raw = (i & 1) ? (u[i >> 1] >> 16) : (u[i >> 1] & 0xffffu);
    const float f = fmaxf(fmaf(bf2f(raw), sc[i], sh[i]), 0.f);
    r[i] = (short)f2bf(f);
  }
  return r;
}

// sorted-insert of packed key pd into top-4 cache (c0<=c1<=c2<=c3)
__device__ __forceinline__ void ins4(double pd, double& c0, double& c1, double& c2, double& c3){
  const double t3 = fmin(c3, pd);
  const double n2 = fmin(c2, t3), x3 = fmax(c2, t3);
  const double n1 = fmin(c1, n2), x2 = fmax(c1, n2);
  const double n0 = fmin(c0, n1), x1 = fmax(c0, n1);
  c0 = n0; c1 = x1; c2 = x2; c3 = x3;
}

// rescan for ONE query with skip mask (rare path) — MUST stay inline: by-ref
// doubles across a real call spill the cache state to scratch (R6 regression).
__device__ __forceinline__ void scan1(const float* xs, const float* ys, const float* zs,
                                      int lane, float qx, float qy, float qz, float src2,
                                      unsigned long long skip,
                                      double& c0, double& c1, double& c2, double& c3){
  for (int e = 0; e < 64; ++e){
    if ((skip >> e) & 1ull) continue;
    const int j = (e << 6) | lane;
    const float px = xs[j], py = ys[j], pz = zs[j];
    const float dst2 = (px*px + py*py) + pz*pz;
    const float dot  = (qx*px + qy*py) + qz*pz;
    const float d = fmaf(dot, -2.f, src2 + dst2);
    const unsigned long long uu =
        (unsigned long long)__double_as_longlong((double)d) | (unsigned)j;
    ins4(__longlong_as_double((long long)uu), c0, c1, c2, c3);
  }
}

// ---------- Kernel 1: top-K=32 NN, TWO queries per wave (interleaved chains) ----------
// key = as_double(d) | j (low 12 mantissa bits; exact order (d, j)).
// Block 0 also zeroes the stats accumulators (512 floats).
__global__ __launch_bounds__(512) void topk_kernel(const float* __restrict__ xyz,
                                                   int* __restrict__ idx_out,
                                                   float* __restrict__ statsacc){
  __shared__ float xs[NPTS], ys[NPTS], zs[NPTS];   // 48 KB
  const int tid = threadIdx.x;
  if (blockIdx.x == 0 && tid < 512) statsacc[tid] = 0.f;

  const int b = blockIdx.x >> 6;         // 64 blocks per batch, 16 queries/block
  const float* xb = xyz + (size_t)b * NPTS * 3;
  for (int p = tid; p < NPTS; p += 512){
    xs[p] = xb[3*p + 0];
    ys[p] = xb[3*p + 1];
    zs[p] = xb[3*p + 2];
  }
  __syncthreads();

  const int wv   = tid >> 6;
  const int lane = tid & 63;
  const int qA   = blockIdx.x * 16 + wv*2;    // two queries per wave
  const int qB   = qA + 1;
  const int sA_  = qA & (NQ - 1);
  const int sB_  = qB & (NQ - 1);

  const float axq = xs[sA_], ayq = ys[sA_], azq = zs[sA_];
  const float bxq = xs[sB_], byq = ys[sB_], bzq = zs[sB_];
  const float src2A = (axq*axq + ayq*ayq) + azq*azq;
  const float src2B = (bxq*bxq + byq*byq) + bzq*bzq;

  const double DINF = __builtin_inf();
  double a0 = DINF, a1 = DINF, a2 = DINF, a3 = DINF;
  double b0 = DINF, b1 = DINF, b2 = DINF, b3 = DINF;

  // init scan: shared point loads, dual independent insert chains
  for (int e = 0; e < 64; ++e){
    const int j = (e << 6) | lane;
    const float px = xs[j], py = ys[j], pz = zs[j];
    const float dst2 = (px*px + py*py) + pz*pz;
    const float dotA = (axq*px + ayq*py) + azq*pz;
    const float dotB = (bxq*px + byq*py) + bzq*pz;
    const float dA = fmaf(dotA, -2.f, src2A + dst2);
    const float dB = fmaf(dotB, -2.f, src2B + dst2);
    const unsigned long long uA =
        (unsigned long long)__double_as_longlong((double)dA) | (unsigned)j;
    const unsigned long long uB =
        (unsigned long long)__double_as_longlong((double)dB) | (unsigned)j;
    ins4(__longlong_as_double((long long)uA), a0, a1, a2, a3);
    ins4(__longlong_as_double((long long)uB), b0, b1, b2, b3);
  }

  unsigned long long skipA = 0ull, skipB = 0ull;
  int ncA = 4, ncB = 4;
  int winA = 0, winB = 0;

  #pragma unroll 1
  for (int it = 0; it < KNN; ++it){
    double wA = a0, wB = b0;
    #pragma unroll
    for (int m = 32; m >= 1; m >>= 1){
      wA = fmin(wA, __shfl_xor(wA, m, 64));
      wB = fmin(wB, __shfl_xor(wB, m, 64));
    }
    if (lane == it){
      winA = (int)((unsigned)__double_as_longlong(wA) & 0xFFFu);
      winB = (int)((unsigned)__double_as_longlong(wB) & 0xFFFu);
    }
    if (a0 == wA){                  // unique keys -> exactly one lane
      const unsigned lo = (unsigned)__double_as_longlong(a0);
      skipA |= 1ull << ((lo >> 6) & 63u);
      a0 = a1; a1 = a2; a2 = a3; a3 = DINF;
      if (--ncA == 0){
        a0 = a1 = a2 = a3 = DINF;
        scan1(xs, ys, zs, lane, axq, ayq, azq, src2A, skipA, a0, a1, a2, a3);
        ncA = 4;
      }
    }
    if (b0 == wB){
      const unsigned lo = (unsigned)__double_as_longlong(b0);
      skipB |= 1ull << ((lo >> 6) & 63u);
      b0 = b1; b1 = b2; b2 = b3; b3 = DINF;
      if (--ncB == 0){
        b0 = b1 = b2 = b3 = DINF;
        scan1(xs, ys, zs, lane, bxq, byq, bzq, src2B, skipB, b0, b1, b2, b3);
        ncB = 4;
      }
    }
  }
  if (lane < KNN){
    idx_out[qA * KNN + lane] = winA;
    idx_out[qB * KNN + lane] = winB;
  }
}

// ---------- Layer 0: gather + concat + MFMA GEMM (K padded 67->96), fused stats ----------
__global__ __launch_bounds__(256) void l0_mfma(const float* __restrict__ xyz,
                                               const float* __restrict__ pts,
                                               const int*   __restrict__ idxbuf,
                                               const float* __restrict__ W,     // (64,67)
                                               const float* __restrict__ bias,  // (64)
                                               unsigned short* __restrict__ hout,
                                               float* __restrict__ acc){
  __shared__ short lds[256*104];
  __shared__ float sacc[128];
  const int tid = threadIdx.x;
  if (tid < 128) sacc[tid] = 0.f;
  const int lane = tid & 63, wv = tid >> 6;
  const int m16 = lane & 15, kg = lane >> 4;

  short8 Bf[4][3];
  float  bl[4];
  for (int ocb = 0; ocb < 4; ++ocb){
    const int n = ocb*16 + m16;
    bl[ocb] = bias[n];
    for (int ks = 0; ks < 3; ++ks){
      short8 t;
      #pragma unroll
      for (int i = 0; i < 8; ++i){
        const int k = ks*32 + kg*8 + i;
        float wv_ = 0.f;
        if (k < 64) wv_ = W[n*67 + 3 + k];
        else if (k < 67) wv_ = W[n*67 + (k - 64)];
        t[i] = (short)f2bf(wv_);
      }
      Bf[ocb][ks] = t;
    }
  }

  {
    const int row = blockIdx.x*256 + tid;
    const int rowq = row >> 5;
    const int b = rowq >> 10, s = rowq & 1023;
    const int j = idxbuf[row];
    const float4* p4 = (const float4*)(pts + ((size_t)b*NPTS + j)*64);
    short* myrow = lds + tid*104;
    #pragma unroll
    for (int u = 0; u < 8; ++u){
      float4 x = p4[2*u], y = p4[2*u+1];
      short8 o;
      o[0]=(short)f2bf(x.x); o[1]=(short)f2bf(x.y); o[2]=(short)f2bf(x.z); o[3]=(short)f2bf(x.w);
      o[4]=(short)f2bf(y.x); o[5]=(short)f2bf(y.y); o[6]=(short)f2bf(y.z); o[7]=(short)f2bf(y.w);
      *(short8*)(myrow + u*8) = o;
    }
    const float* pj = xyz + ((size_t)b*NPTS + j)*3;
    const float* ps = xyz + ((size_t)b*NPTS + s)*3;
    short8 z = 0;
    z[0] = (short)f2bf(pj[0]-ps[0]);
    z[1] = (short)f2bf(pj[1]-ps[1]);
    z[2] = (short)f2bf(pj[2]-ps[2]);
    *(short8*)(myrow + 64) = z;
    short8 zz = 0;
    *(short8*)(myrow + 72) = zz;
    *(short8*)(myrow + 80) = zz;
    *(short8*)(myrow + 88) = zz;
  }
  __syncthreads();

  float sA[4] = {0,0,0,0}, qA[4] = {0,0,0,0};
  const int rowbase = blockIdx.x*256 + wv*64;
  for (int rt = 0; rt < 4; ++rt){
    const short* ar = lds + (wv*64 + rt*16 + m16)*104;
    short8 a0 = *(const short8*)(ar + kg*8);
    short8 a1 = *(const short8*)(ar + 32 + kg*8);
    short8 a2 = *(const short8*)(ar + 64 + kg*8);
    #pragma unroll
    for (int ocb = 0; ocb < 4; ++ocb){
      f32x4 c = {bl[ocb], bl[ocb], bl[ocb], bl[ocb]};
      c = __builtin_amdgcn_mfma_f32_16x16x32_bf16(a0, Bf[ocb][0], c, 0, 0, 0);
      c = __builtin_amdgcn_mfma_f32_16x16x32_bf16(a1, Bf[ocb][1], c, 0, 0, 0);
      c = __builtin_amdgcn_mfma_f32_16x16x32_bf16(a2, Bf[ocb][2], c, 0, 0, 0);
      #pragma unroll
      for (int r = 0; r < 4; ++r){
        const float hv = c[r];
        sA[ocb] += hv; qA[ocb] += hv*hv;
        const int orow = rowbase + rt*16 + kg*4 + r;
        hout[(size_t)orow*64 + ocb*16 + m16] = f2bf(hv);
      }
    }
  }
  #pragma unroll
  for (int ocb = 0; ocb < 4; ++ocb){
    float s = sA[ocb], q = qA[ocb];
    s += __shfl_xor(s, 16, 64); s += __shfl_xor(s, 32, 64);
    q += __shfl_xor(q, 16, 64); q += __shfl_xor(q, 32, 64);
    if (kg == 0){
      atomicAdd(&sacc[ocb*16 + m16], s);
      atomicAdd(&sacc[64 + ocb*16 + m16], q);
    }
  }
  __syncthreads();
  if (tid < 128) atomicAdd(&acc[tid], sacc[tid]);
}

// ---------- Layer 1: in-kernel ss0 + norm+relu(A) + MFMA GEMM 64->64, fused stats ----------
__global__ __launch_bounds__(256) void l1_mfma(const unsigned* __restrict__ hin,
                                               const float* __restrict__ acc0,  // (128) sum|sumsq
                                               const float* __restrict__ g,
                                               const float* __restrict__ be,
                                               const float* __restrict__ W,     // (64,64)
                                               const float* __restrict__ bias,  // (64)
                                               unsigned short* __restrict__ hout,
                                               float* __restrict__ acc1){
  __shared__ float ssl[128];
  __shared__ float sacc[128];
  const int tid = threadIdx.x;
  if (tid < 128) sacc[tid] = 0.f;
  if (tid < 64){
    const float invM = 1.f / (float)MROWS;
    const float mean = acc0[tid] * invM;
    const float var  = acc0[64 + tid] * invM - mean*mean;
    const float scale = g[tid] * rsqrtf(var + 1e-5f);
    ssl[2*tid + 0] = scale;
    ssl[2*tid + 1] = be[tid] - mean * scale;
  }
  __syncthreads();

  const int lane = tid & 63, wv = tid >> 6;
  const int m16 = lane & 15, kg = lane >> 4;

  float scl[2][8], shf[2][8];
  #pragma unroll
  for (int s2 = 0; s2 < 2; ++s2)
    #pragma unroll
    for (int i = 0; i < 8; ++i){
      const int c = s2*32 + kg*8 + i;
      scl[s2][i] = ssl[2*c];
      shf[s2][i] = ssl[2*c + 1];
    }

  short8 Bf[4][2];
  float  bl[4];
  for (int ocb = 0; ocb < 4; ++ocb){
    const int n = ocb*16 + m16;
    bl[ocb] = bias[n];
    #pragma unroll
    for (int s2 = 0; s2 < 2; ++s2){
      short8 t;
      #pragma unroll
      for (int i = 0; i < 8; ++i)
        t[i] = (short)f2bf(W[n*64 + s2*32 + kg*8 + i]);
      Bf[ocb][s2] = t;
    }
  }

  float sA[4] = {0,0,0,0}, qA[4] = {0,0,0,0};
  const int rowbase = blockIdx.x*256 + wv*64;
  for (int rt = 0; rt < 4; ++rt){
    const int arow = rowbase + rt*16 + m16;
    const uint4* pr = (const uint4*)hin + (size_t)arow*8;
    uint4 v0 = pr[kg];
    uint4 v1 = pr[4 + kg];
    short8 a0 = norm_frag(v0, scl[0], shf[0]);
    short8 a1 = norm_frag(v1, scl[1], shf[1]);
    #pragma unroll
    for (int ocb = 0; ocb < 4; ++ocb){
      f32x4 c = {bl[ocb], bl[ocb], bl[ocb], bl[ocb]};
      c = __builtin_amdgcn_mfma_f32_16x16x32_bf16(a0, Bf[ocb][0], c, 0, 0, 0);
      c = __builtin_amdgcn_mfma_f32_16x16x32_bf16(a1, Bf[ocb][1], c, 0, 0, 0);
      #pragma unroll
      for (int r = 0; r < 4; ++r){
        const float hv = c[r];
        sA[ocb] += hv; qA[ocb] += hv*hv;
        const int orow = rowbase + rt*16 + kg*4 + r;
        hout[(size_t)orow*64 + ocb*16 + m16] = f2bf(hv);
      }
    }
  }
  #pragma unroll
  for (int ocb = 0; ocb < 4; ++ocb){
    float s = sA[ocb], q = qA[ocb];
    s += __shfl_xor(s, 16, 64); s += __shfl_xor(s, 32, 64);
    q += __shfl_xor(q, 16, 64); q += __shfl_xor(q, 32, 64);
    if (kg == 0){
      atomicAdd(&sacc[ocb*16 + m16], s);
      atomicAdd(&sacc[64 + ocb*16 + m16], q);
    }
  }
  __syncthreads();
  if (tid < 128) atomicAdd(&acc1[tid], sacc[tid]);
}

// ---------- Layer 2 FUSED: in-kernel ss1 + GEMM 64->128 + stats + per-(q,c) max/min ----------
__global__ __launch_bounds__(256) void l2_fused(const unsigned* __restrict__ hin,
                                                const float* __restrict__ acc1,  // (128)
                                                const float* __restrict__ g,
                                                const float* __restrict__ be,
                                                const float* __restrict__ W,     // (128,64)
                                                const float* __restrict__ bias,  // (128)
                                                float* __restrict__ maxb,        // (16384,128)
                                                float* __restrict__ minb,        // (16384,128)
                                                float* __restrict__ acc2){
  __shared__ float ssl[128];
  __shared__ float sacc[256];
  const int tid = threadIdx.x;
  sacc[tid] = 0.f;
  if (tid < 64){
    const float invM = 1.f / (float)MROWS;
    const float mean = acc1[tid] * invM;
    const float var  = acc1[64 + tid] * invM - mean*mean;
    const float scale = g[tid] * rsqrtf(var + 1e-5f);
    ssl[2*tid + 0] = scale;
    ssl[2*tid + 1] = be[tid] - mean * scale;
  }
  __syncthreads();

  const int lane = tid & 63, wv = tid >> 6;
  const int m16 = lane & 15, kg = lane >> 4;

  float scl[2][8], shf[2][8];
  #pragma unroll
  for (int s2 = 0; s2 < 2; ++s2)
    #pragma unroll
    for (int i = 0; i < 8; ++i){
      const int c = s2*32 + kg*8 + i;
      scl[s2][i] = ssl[2*c];
      shf[s2][i] = ssl[2*c + 1];
    }

  short8 Bf[8][2];
  float  bl[8];
  for (int ocb = 0; ocb < 8; ++ocb){
    const int n = ocb*16 + m16;
    bl[ocb] = bias[n];
    #pragma unroll
    for (int s2 = 0; s2 < 2; ++s2){
      short8 t;
      #pragma unroll
      for (int i = 0; i < 8; ++i)
        t[i] = (short)f2bf(W[n*64 + s2*32 + kg*8 + i]);
      Bf[ocb][s2] = t;
    }
  }

  float sA[8], qA[8];
  float mx[2][8], mn[2][8];
  #pragma unroll
  for (int o = 0; o < 8; ++o){
    sA[o] = 0.f; qA[o] = 0.f;
    mx[0][o] = -FLT_MAX_; mx[1][o] = -FLT_MAX_;
    mn[0][o] =  FLT_MAX_; mn[1][o] =  FLT_MAX_;
  }

  const int rowbase = blockIdx.x*256 + wv*64;   // 2 queries per wave
  #pragma unroll
  for (int rt = 0; rt < 4; ++rt){
    const int qs = rt >> 1;
    const int arow = rowbase + rt*16 + m16;
    const uint4* pr = (const uint4*)hin + (size_t)arow*8;
    uint4 v0 = pr[kg];
    uint4 v1 = pr[4 + kg];
    short8 a0 = norm_frag(v0, scl[0], shf[0]);
    short8 a1 = norm_frag(v1, scl[1], shf[1]);
    #pragma unroll
    for (int ocb = 0; ocb < 8; ++ocb){
      f32x4 c = {bl[ocb], bl[ocb], bl[ocb], bl[ocb]};
      c = __builtin_amdgcn_mfma_f32_16x16x32_bf16(a0, Bf[ocb][0], c, 0, 0, 0);
      c = __builtin_amdgcn_mfma_f32_16x16x32_bf16(a1, Bf[ocb][1], c, 0, 0, 0);
      #pragma unroll
      for (int r = 0; r < 4; ++r){
        const float hv = c[r];
        sA[ocb] += hv; qA[ocb] += hv*hv;
        mx[qs][ocb] = fmaxf(mx[qs][ocb], hv);
        mn[qs][ocb] = fminf(mn[qs][ocb], hv);
      }
    }
  }

  #pragma unroll
  for (int ocb = 0; ocb < 8; ++ocb){
    float s = sA[ocb], q = qA[ocb];
    s += __shfl_xor(s, 16, 64); s += __shfl_xor(s, 32, 64);
    q += __shfl_xor(q, 16, 64); q += __shfl_xor(q, 32, 64);
    if (kg == 0){
      atomicAdd(&sacc[ocb*16 + m16], s);
      atomicAdd(&sacc[128 + ocb*16 + m16], q);
    }
  }

  const int qa = rowbase >> 5;
  #pragma unroll
  for (int qs = 0; qs < 2; ++qs)
    #pragma unroll
    for (int ocb = 0; ocb < 8; ++ocb){
      float a = mx[qs][ocb], b = mn[qs][ocb];
      a = fmaxf(a, __shfl_xor(a, 16, 64)); a = fmaxf(a, __shfl_xor(a, 32, 64));
      b = fminf(b, __shfl_xor(b, 16, 64)); b = fminf(b, __shfl_xor(b, 32, 64));
      if (kg == 0){
        maxb[(size_t)(qa + qs)*128 + ocb*16 + m16] = a;
        minb[(size_t)(qa + qs)*128 + ocb*16 + m16] = b;
      }
    }

  __syncthreads();
  atomicAdd(&acc2[tid], sacc[tid]);
}

// ---------- Final: in-kernel ss2; out = relu(scale*(scale>=0?max:min)+shift); new_xyz ----------
__global__ __launch_bounds__(256) void final_kernel(const float* __restrict__ xyz,
                                                    const float* __restrict__ maxb,
                                                    const float* __restrict__ minb,
                                                    const float* __restrict__ acc2, // (256)
                                                    const float* __restrict__ g,
                                                    const float* __restrict__ be,
                                                    float* __restrict__ out){
  __shared__ float ssl[256];
  const int tid = threadIdx.x;
  if (tid < 128){
    const float invM = 1.f / (float)MROWS;
    const float mean = acc2[tid] * invM;
    const float var  = acc2[128 + tid] * invM - mean*mean;
    const float scale = g[tid] * rsqrtf(var + 1e-5f);
    ssl[2*tid + 0] = scale;
    ssl[2*tid + 1] = be[tid] - mean * scale;
  }
  __syncthreads();

  const int q = blockIdx.x * 4 + (tid >> 6);
  const int p = tid & 63;          // channel pair 0..63 (128 channels)
  const float sc0 = ssl[4*p + 0], sh0 = ssl[4*p + 1];
  const float sc1 = ssl[4*p + 2], sh1 = ssl[4*p + 3];
  const float2 mxv = ((const float2*)(maxb + (size_t)q*128))[p];
  const float2 mnv = ((const float2*)(minb + (size_t)q*128))[p];
  const float h0v = (sc0 >= 0.f) ? mxv.x : mnv.x;
  const float h1v = (sc1 >= 0.f) ? mxv.y : mnv.y;
  float2 r;
  r.x = fmaxf(fmaf(sc0, h0v, sh0), 0.f);
  r.y = fmaxf(fmaf(sc1, h1v, sh1), 0.f);
  ((float2*)(out + (size_t)NB*NQ*3))[(size_t)q*64 + p] = r;
  if (p < 3){
    const int b_ = q >> 10, s = q & 1023;
    out[(size_t)q*3 + p] = xyz[((size_t)b_ * NPTS + s)*3 + p];
  }
}

// ---------- host ----------
extern "C" void kernel_launch(void* const* d_in, const int* in_sizes, int n_in,
                              void* d_out, int out_size, void* d_ws, size_t ws_size,
                              hipStream_t stream){
  (void)in_sizes; (void)n_in; (void)out_size; (void)ws_size;
  const float* xyz = (const float*)d_in[0];
  const float* pts = (const float*)d_in[1];
  const float* W0  = (const float*)d_in[2];
  const float* b0  = (const float*)d_in[3];
  const float* g0  = (const float*)d_in[4];
  const float* be0 = (const float*)d_in[5];
  const float* W1  = (const float*)d_in[6];
  const float* b1  = (const float*)d_in[7];
  const float* g1  = (const float*)d_in[8];
  const float* be1 = (const float*)d_in[9];
  const float* W2  = (const float*)d_in[10];
  const float* b2  = (const float*)d_in[11];
  const float* g2  = (const float*)d_in[12];
  const float* be2 = (const float*)d_in[13];

  // workspace: idx 2MB | acc 512f | h0 64MB | h1 64MB  (~130 MB)
  // max/min buffers (8MB each) reuse the h0 region (dead after l1).
  char* ws = (char*)d_ws;
  int*   idx = (int*)ws;
  float* acc = (float*)(ws + 2097152);
  unsigned* h0 = (unsigned*)(ws + 2101248);
  unsigned* h1 = (unsigned*)(ws + 2101248 + 67108864);
  float* maxb = (float*)h0;
  float* minb = maxb + (size_t)16384*128;
  float* out = (float*)d_out;

  float* acc0 = acc, *acc1 = acc + 128, *acc2 = acc + 256;   // acc2: 256 floats

  topk_kernel<<<1024, 512, 0, stream>>>(xyz, idx, acc);
  l0_mfma<<<2048, 256, 0, stream>>>(xyz, pts, idx, W0, b0, (unsigned short*)h0, acc0);
  l1_mfma<<<2048, 256, 0, stream>>>(h0, acc0, g0, be0, W1, b1, (unsigned short*)h1, acc1);
  l2_fused<<<2048, 256, 0, stream>>>(h1, acc1, g1, be1, W2, b2, maxb, minb, acc2);
  final_kernel<<<4096, 256, 0, stream>>>(xyz, maxb, minb, acc2, g2, be2, out);
}

// Round 8
// 300.339 us; speedup vs baseline: 1.5167x; 1.1137x over previous
//
#include <hip/hip_runtime.h>

#define NPTS 4096
#define NQ   1024     // S
#define NB   16       // B
#define KNN  32
#define MROWS 524288  // B*S*K
#define FLT_MAX_ 3.402823466e+38f

typedef __attribute__((ext_vector_type(8))) short short8;
typedef __attribute__((ext_vector_type(4))) float f32x4;

// ---------- bf16 helpers ----------
__device__ inline unsigned short f2bf(float x){
  unsigned u = __float_as_uint(x);
  u += 0x7fffu + ((u >> 16) & 1u);
  return (unsigned short)(u >> 16);
}
// HW packed f32->bf16 (RNE): low16 = cvt(lo), high16 = cvt(hi)
__device__ __forceinline__ unsigned cvt_pk_bf16(float lo, float hi){
  unsigned r;
  asm("v_cvt_pk_bf16_f32 %0, %1, %2" : "=v"(r) : "v"(lo), "v"(hi));
  return r;
}

// normalize+relu 8 bf16 (one A-fragment k-slice) -> bf16 frag, via cvt_pk
__device__ __forceinline__ short8 norm_frag(uint4 v, const float* sc, const float* sh){
  const unsigned u[4] = {v.x, v.y, v.z, v.w};
  unsigned w[4];
  #pragma unroll
  for (int t = 0; t < 4; ++t){
    float lo = __uint_as_float(u[t] << 16);
    float hi = __uint_as_float(u[t] & 0xffff0000u);
    lo = fmaxf(fmaf(lo, sc[2*t+0], sh[2*t+0]), 0.f);
    hi = fmaxf(fmaf(hi, sc[2*t+1], sh[2*t+1]), 0.f);
    w[t] = cvt_pk_bf16(lo, hi);
  }
  union { uint4 u4; short8 s8; } cv;
  cv.u4.x = w[0]; cv.u4.y = w[1]; cv.u4.z = w[2]; cv.u4.w = w[3];
  return cv.s8;
}

// sorted-insert of packed key pd into top-4 cache (c0<=c1<=c2<=c3)
__device__ __forceinline__ void ins4(double pd, double& c0, double& c1, double& c2, double& c3){
  const double t3 = fmin(c3, pd);
  const double n2 = fmin(c2, t3), x3 = fmax(c2, t3);
  const double n1 = fmin(c1, n2), x2 = fmax(c1, n2);
  const double n0 = fmin(c0, n1), x1 = fmax(c0, n1);
  c0 = n0; c1 = x1; c2 = x2; c3 = x3;
}

// rescan for ONE query with skip mask (rare path) — MUST stay inline (R6 spill lesson)
__device__ __forceinline__ void scan1(const float* xs, const float* ys, const float* zs,
                                      int lane, float qx, float qy, float qz, float src2,
                                      unsigned long long skip,
                                      double& c0, double& c1, double& c2, double& c3){
  for (int e = 0; e < 64; ++e){
    if ((skip >> e) & 1ull) continue;
    const int j = (e << 6) | lane;
    const float px = xs[j], py = ys[j], pz = zs[j];
    const float dst2 = (px*px + py*py) + pz*pz;
    const float dot  = (qx*px + qy*py) + qz*pz;
    const float d = fmaf(dot, -2.f, src2 + dst2);
    const unsigned long long uu =
        (unsigned long long)__double_as_longlong((double)d) | (unsigned)j;
    ins4(__longlong_as_double((long long)uu), c0, c1, c2, c3);
  }
}

// ---------- Kernel 1: top-K=32 NN, TWO queries per wave (interleaved chains) ----------
__global__ __launch_bounds__(512) void topk_kernel(const float* __restrict__ xyz,
                                                   int* __restrict__ idx_out,
                                                   float* __restrict__ statsacc){
  __shared__ float xs[NPTS], ys[NPTS], zs[NPTS];   // 48 KB
  const int tid = threadIdx.x;
  if (blockIdx.x == 0 && tid < 512) statsacc[tid] = 0.f;

  const int b = blockIdx.x >> 6;         // 64 blocks per batch, 16 queries/block
  const float* xb = xyz + (size_t)b * NPTS * 3;
  for (int p = tid; p < NPTS; p += 512){
    xs[p] = xb[3*p + 0];
    ys[p] = xb[3*p + 1];
    zs[p] = xb[3*p + 2];
  }
  __syncthreads();

  const int wv   = tid >> 6;
  const int lane = tid & 63;
  const int qA   = blockIdx.x * 16 + wv*2;
  const int qB   = qA + 1;
  const int sA_  = qA & (NQ - 1);
  const int sB_  = qB & (NQ - 1);

  const float axq = xs[sA_], ayq = ys[sA_], azq = zs[sA_];
  const float bxq = xs[sB_], byq = ys[sB_], bzq = zs[sB_];
  const float src2A = (axq*axq + ayq*ayq) + azq*azq;
  const float src2B = (bxq*bxq + byq*byq) + bzq*bzq;

  const double DINF = __builtin_inf();
  double a0 = DINF, a1 = DINF, a2 = DINF, a3 = DINF;
  double b0 = DINF, b1 = DINF, b2 = DINF, b3 = DINF;

  for (int e = 0; e < 64; ++e){
    const int j = (e << 6) | lane;
    const float px = xs[j], py = ys[j], pz = zs[j];
    const float dst2 = (px*px + py*py) + pz*pz;
    const float dotA = (axq*px + ayq*py) + azq*pz;
    const float dotB = (bxq*px + byq*py) + bzq*pz;
    const float dA = fmaf(dotA, -2.f, src2A + dst2);
    const float dB = fmaf(dotB, -2.f, src2B + dst2);
    const unsigned long long uA =
        (unsigned long long)__double_as_longlong((double)dA) | (unsigned)j;
    const unsigned long long uB =
        (unsigned long long)__double_as_longlong((double)dB) | (unsigned)j;
    ins4(__longlong_as_double((long long)uA), a0, a1, a2, a3);
    ins4(__longlong_as_double((long long)uB), b0, b1, b2, b3);
  }

  unsigned long long skipA = 0ull, skipB = 0ull;
  int ncA = 4, ncB = 4;
  int winA = 0, winB = 0;

  #pragma unroll 1
  for (int it = 0; it < KNN; ++it){
    double wA = a0, wB = b0;
    #pragma unroll
    for (int m = 32; m >= 1; m >>= 1){
      wA = fmin(wA, __shfl_xor(wA, m, 64));
      wB = fmin(wB, __shfl_xor(wB, m, 64));
    }
    if (lane == it){
      winA = (int)((unsigned)__double_as_longlong(wA) & 0xFFFu);
      winB = (int)((unsigned)__double_as_longlong(wB) & 0xFFFu);
    }
    if (a0 == wA){
      const unsigned lo = (unsigned)__double_as_longlong(a0);
      skipA |= 1ull << ((lo >> 6) & 63u);
      a0 = a1; a1 = a2; a2 = a3; a3 = DINF;
      if (--ncA == 0){
        a0 = a1 = a2 = a3 = DINF;
        scan1(xs, ys, zs, lane, axq, ayq, azq, src2A, skipA, a0, a1, a2, a3);
        ncA = 4;
      }
    }
    if (b0 == wB){
      const unsigned lo = (unsigned)__double_as_longlong(b0);
      skipB |= 1ull << ((lo >> 6) & 63u);
      b0 = b1; b1 = b2; b2 = b3; b3 = DINF;
      if (--ncB == 0){
        b0 = b1 = b2 = b3 = DINF;
        scan1(xs, ys, zs, lane, bxq, byq, bzq, src2B, skipB, b0, b1, b2, b3);
        ncB = 4;
      }
    }
  }
  if (lane < KNN){
    idx_out[qA * KNN + lane] = winA;
    idx_out[qB * KNN + lane] = winB;
  }
}

// ---------- Layer 0: gather + concat + SWAPPED MFMA GEMM (K padded 67->96), fused stats ----------
// mfma(Wf, Xf, c): D reg r at lane (kg,m16) = h[ch = cg*16+kg*4+r][row tile m16]
// -> per lane 4 consecutive channels of one row: pack 2x cvt_pk, store dwordx2.
__global__ __launch_bounds__(256) void l0_mfma(const float* __restrict__ xyz,
                                               const float* __restrict__ pts,
                                               const int*   __restrict__ idxbuf,
                                               const float* __restrict__ W,     // (64,67)
                                               const float* __restrict__ bias,  // (64)
                                               unsigned short* __restrict__ hout,
                                               float* __restrict__ acc){
  __shared__ short lds[256*104];
  __shared__ float sacc[128];
  const int tid = threadIdx.x;
  if (tid < 128) sacc[tid] = 0.f;
  const int lane = tid & 63, wv = tid >> 6;
  const int m16 = lane & 15, kg = lane >> 4;

  // W fragments (FIRST operand): lane holds W[ch=cg*16+m16][k=kg*8+i]
  short8 Wf[4][3];
  f32x4  bl4[4];
  for (int cg = 0; cg < 4; ++cg){
    bl4[cg] = *(const f32x4*)(bias + cg*16 + kg*4);
    const int n = cg*16 + m16;
    for (int ks = 0; ks < 3; ++ks){
      short8 t;
      #pragma unroll
      for (int i = 0; i < 8; ++i){
        const int k = ks*32 + kg*8 + i;
        float wv_ = 0.f;
        if (k < 64) wv_ = W[n*67 + 3 + k];
        else if (k < 67) wv_ = W[n*67 + (k - 64)];
        t[i] = (short)f2bf(wv_);
      }
      Wf[cg][ks] = t;
    }
  }

  // stage one row per thread (cvt_pk packing)
  {
    const int row = blockIdx.x*256 + tid;
    const int rowq = row >> 5;
    const int b = rowq >> 10, s = rowq & 1023;
    const int j = idxbuf[row];
    const float4* p4 = (const float4*)(pts + ((size_t)b*NPTS + j)*64);
    short* myrow = lds + tid*104;
    #pragma unroll
    for (int u = 0; u < 8; ++u){
      float4 x = p4[2*u], y = p4[2*u+1];
      uint4 o;
      o.x = cvt_pk_bf16(x.x, x.y);
      o.y = cvt_pk_bf16(x.z, x.w);
      o.z = cvt_pk_bf16(y.x, y.y);
      o.w = cvt_pk_bf16(y.z, y.w);
      *(uint4*)(myrow + u*8) = o;
    }
    const float* pj = xyz + ((size_t)b*NPTS + j)*3;
    const float* ps = xyz + ((size_t)b*NPTS + s)*3;
    uint4 z;
    z.x = cvt_pk_bf16(pj[0]-ps[0], pj[1]-ps[1]);
    z.y = cvt_pk_bf16(pj[2]-ps[2], 0.f);
    z.z = 0u; z.w = 0u;
    *(uint4*)(myrow + 64) = z;
    uint4 zz; zz.x = zz.y = zz.z = zz.w = 0u;
    *(uint4*)(myrow + 72) = zz;
    *(uint4*)(myrow + 80) = zz;
    *(uint4*)(myrow + 88) = zz;
  }
  __syncthreads();

  f32x4 zero4 = {0.f, 0.f, 0.f, 0.f};
  f32x4 sA[4] = {zero4, zero4, zero4, zero4};
  f32x4 qA[4] = {zero4, zero4, zero4, zero4};

  const int rowbase = blockIdx.x*256 + wv*64;
  for (int rt = 0; rt < 4; ++rt){
    const short* ar = lds + (wv*64 + rt*16 + m16)*104;
    short8 x0 = *(const short8*)(ar + kg*8);
    short8 x1 = *(const short8*)(ar + 32 + kg*8);
    short8 x2 = *(const short8*)(ar + 64 + kg*8);
    const size_t rbase = (size_t)(rowbase + rt*16 + m16) * 64;
    #pragma unroll
    for (int cg = 0; cg < 4; ++cg){
      f32x4 c = bl4[cg];
      c = __builtin_amdgcn_mfma_f32_16x16x32_bf16(Wf[cg][0], x0, c, 0, 0, 0);
      c = __builtin_amdgcn_mfma_f32_16x16x32_bf16(Wf[cg][1], x1, c, 0, 0, 0);
      c = __builtin_amdgcn_mfma_f32_16x16x32_bf16(Wf[cg][2], x2, c, 0, 0, 0);
      sA[cg] += c; qA[cg] += c*c;
      uint2 o;
      o.x = cvt_pk_bf16(c[0], c[1]);
      o.y = cvt_pk_bf16(c[2], c[3]);
      *(uint2*)(hout + rbase + cg*16 + kg*4) = o;
    }
  }
  // reduce stats over the 16 row-lanes (m16)
  #pragma unroll
  for (int cg = 0; cg < 4; ++cg)
    #pragma unroll
    for (int m = 1; m <= 8; m <<= 1)
      #pragma unroll
      for (int t = 0; t < 4; ++t){
        sA[cg][t] += __shfl_xor(sA[cg][t], m, 64);
        qA[cg][t] += __shfl_xor(qA[cg][t], m, 64);
      }
  if (m16 == 0){
    #pragma unroll
    for (int cg = 0; cg < 4; ++cg)
      #pragma unroll
      for (int t = 0; t < 4; ++t){
        atomicAdd(&sacc[cg*16 + kg*4 + t], sA[cg][t]);
        atomicAdd(&sacc[64 + cg*16 + kg*4 + t], qA[cg][t]);
      }
  }
  __syncthreads();
  if (tid < 128) atomicAdd(&acc[tid], sacc[tid]);
}

// ---------- Layer 1: in-kernel ss0 + norm+relu + SWAPPED MFMA 64->64, fused stats ----------
// 1024 blocks x 2 row-tiles (amortizes W-frag setup).
__global__ __launch_bounds__(256) void l1_mfma(const unsigned* __restrict__ hin,
                                               const float* __restrict__ acc0,  // (128) sum|sumsq
                                               const float* __restrict__ g,
                                               const float* __restrict__ be,
                                               const float* __restrict__ W,     // (64,64)
                                               const float* __restrict__ bias,  // (64)
                                               unsigned short* __restrict__ hout,
                                               float* __restrict__ acc1){
  __shared__ float ssl[128];
  __shared__ float sacc[128];
  const int tid = threadIdx.x;
  if (tid < 128) sacc[tid] = 0.f;
  if (tid < 64){
    const float invM = 1.f / (float)MROWS;
    const float mean = acc0[tid] * invM;
    const float var  = acc0[64 + tid] * invM - mean*mean;
    const float scale = g[tid] * rsqrtf(var + 1e-5f);
    ssl[2*tid + 0] = scale;
    ssl[2*tid + 1] = be[tid] - mean * scale;
  }
  __syncthreads();

  const int lane = tid & 63, wv = tid >> 6;
  const int m16 = lane & 15, kg = lane >> 4;

  float scl[2][8], shf[2][8];
  #pragma unroll
  for (int s2 = 0; s2 < 2; ++s2)
    #pragma unroll
    for (int i = 0; i < 8; ++i){
      const int c = s2*32 + kg*8 + i;
      scl[s2][i] = ssl[2*c];
      shf[s2][i] = ssl[2*c + 1];
    }

  short8 Wf[4][2];
  f32x4  bl4[4];
  for (int cg = 0; cg < 4; ++cg){
    bl4[cg] = *(const f32x4*)(bias + cg*16 + kg*4);
    const int n = cg*16 + m16;
    #pragma unroll
    for (int s2 = 0; s2 < 2; ++s2){
      short8 t;
      #pragma unroll
      for (int i = 0; i < 8; ++i)
        t[i] = (short)f2bf(W[n*64 + s2*32 + kg*8 + i]);
      Wf[cg][s2] = t;
    }
  }

  f32x4 zero4 = {0.f, 0.f, 0.f, 0.f};
  f32x4 sA[4] = {zero4, zero4, zero4, zero4};
  f32x4 qA[4] = {zero4, zero4, zero4, zero4};

  for (int tt = 0; tt < 2; ++tt){
    const int rowbase = (blockIdx.x*2 + tt)*256 + wv*64;
    for (int rt = 0; rt < 4; ++rt){
      const int arow = rowbase + rt*16 + m16;
      const uint4* pr = (const uint4*)hin + (size_t)arow*8;
      uint4 v0 = pr[kg];
      uint4 v1 = pr[4 + kg];
      short8 x0 = norm_frag(v0, scl[0], shf[0]);
      short8 x1 = norm_frag(v1, scl[1], shf[1]);
      const size_t rbase = (size_t)arow * 64;
      #pragma unroll
      for (int cg = 0; cg < 4; ++cg){
        f32x4 c = bl4[cg];
        c = __builtin_amdgcn_mfma_f32_16x16x32_bf16(Wf[cg][0], x0, c, 0, 0, 0);
        c = __builtin_amdgcn_mfma_f32_16x16x32_bf16(Wf[cg][1], x1, c, 0, 0, 0);
        sA[cg] += c; qA[cg] += c*c;
        uint2 o;
        o.x = cvt_pk_bf16(c[0], c[1]);
        o.y = cvt_pk_bf16(c[2], c[3]);
        *(uint2*)(hout + rbase + cg*16 + kg*4) = o;
      }
    }
  }
  #pragma unroll
  for (int cg = 0; cg < 4; ++cg)
    #pragma unroll
    for (int m = 1; m <= 8; m <<= 1)
      #pragma unroll
      for (int t = 0; t < 4; ++t){
        sA[cg][t] += __shfl_xor(sA[cg][t], m, 64);
        qA[cg][t] += __shfl_xor(qA[cg][t], m, 64);
      }
  if (m16 == 0){
    #pragma unroll
    for (int cg = 0; cg < 4; ++cg)
      #pragma unroll
      for (int t = 0; t < 4; ++t){
        atomicAdd(&sacc[cg*16 + kg*4 + t], sA[cg][t]);
        atomicAdd(&sacc[64 + cg*16 + kg*4 + t], qA[cg][t]);
      }
  }
  __syncthreads();
  if (tid < 128) atomicAdd(&acc1[tid], sacc[tid]);
}

// ---------- Layer 2 FUSED: in-kernel ss1 + GEMM 64->128 + stats + per-(q,c) max/min ----------
// Original orientation (no per-row stores; minmax reduce is cheap here). 1024 blocks x 2 tiles.
__global__ __launch_bounds__(256) void l2_fused(const unsigned* __restrict__ hin,
                                                const float* __restrict__ acc1,  // (128)
                                                const float* __restrict__ g,
                                                const float* __restrict__ be,
                                                const float* __restrict__ W,     // (128,64)
                                                const float* __restrict__ bias,  // (128)
                                                float* __restrict__ maxb,        // (16384,128)
                                                float* __restrict__ minb,        // (16384,128)
                                                float* __restrict__ acc2){
  __shared__ float ssl[128];
  __shared__ float sacc[256];
  const int tid = threadIdx.x;
  sacc[tid] = 0.f;
  if (tid < 64){
    const float invM = 1.f / (float)MROWS;
    const float mean = acc1[tid] * invM;
    const float var  = acc1[64 + tid] * invM - mean*mean;
    const float scale = g[tid] * rsqrtf(var + 1e-5f);
    ssl[2*tid + 0] = scale;
    ssl[2*tid + 1] = be[tid] - mean * scale;
  }
  __syncthreads();

  const int lane = tid & 63, wv = tid >> 6;
  const int m16 = lane & 15, kg = lane >> 4;

  float scl[2][8], shf[2][8];
  #pragma unroll
  for (int s2 = 0; s2 < 2; ++s2)
    #pragma unroll
    for (int i = 0; i < 8; ++i){
      const int c = s2*32 + kg*8 + i;
      scl[s2][i] = ssl[2*c];
      shf[s2][i] = ssl[2*c + 1];
    }

  short8 Bf[8][2];
  float  bl[8];
  for (int ocb = 0; ocb < 8; ++ocb){
    const int n = ocb*16 + m16;
    bl[ocb] = bias[n];
    #pragma unroll
    for (int s2 = 0; s2 < 2; ++s2){
      short8 t;
      #pragma unroll
      for (int i = 0; i < 8; ++i)
        t[i] = (short)f2bf(W[n*64 + s2*32 + kg*8 + i]);
      Bf[ocb][s2] = t;
    }
  }

  float sA[8], qA[8];
  #pragma unroll
  for (int o = 0; o < 8; ++o){ sA[o] = 0.f; qA[o] = 0.f; }

  for (int tt = 0; tt < 2; ++tt){
    const int rowbase = (blockIdx.x*2 + tt)*256 + wv*64;   // 2 queries per wave
    float mx[2][8], mn[2][8];
    #pragma unroll
    for (int o = 0; o < 8; ++o){
      mx[0][o] = -FLT_MAX_; mx[1][o] = -FLT_MAX_;
      mn[0][o] =  FLT_MAX_; mn[1][o] =  FLT_MAX_;
    }
    #pragma unroll
    for (int rt = 0; rt < 4; ++rt){
      const int qs = rt >> 1;
      const int arow = rowbase + rt*16 + m16;
      const uint4* pr = (const uint4*)hin + (size_t)arow*8;
      uint4 v0 = pr[kg];
      uint4 v1 = pr[4 + kg];
      short8 a0 = norm_frag(v0, scl[0], shf[0]);
      short8 a1 = norm_frag(v1, scl[1], shf[1]);
      #pragma unroll
      for (int ocb = 0; ocb < 8; ++ocb){
        f32x4 c = {bl[ocb], bl[ocb], bl[ocb], bl[ocb]};
        c = __builtin_amdgcn_mfma_f32_16x16x32_bf16(a0, Bf[ocb][0], c, 0, 0, 0);
        c = __builtin_amdgcn_mfma_f32_16x16x32_bf16(a1, Bf[ocb][1], c, 0, 0, 0);
        #pragma unroll
        for (int r = 0; r < 4; ++r){
          const float hv = c[r];
          sA[ocb] += hv; qA[ocb] += hv*hv;
          mx[qs][ocb] = fmaxf(mx[qs][ocb], hv);
          mn[qs][ocb] = fminf(mn[qs][ocb], hv);
        }
      }
    }
    const int qa = rowbase >> 5;
    #pragma unroll
    for (int qs = 0; qs < 2; ++qs)
      #pragma unroll
      for (int ocb = 0; ocb < 8; ++ocb){
        float a = mx[qs][ocb], b = mn[qs][ocb];
        a = fmaxf(a, __shfl_xor(a, 16, 64)); a = fmaxf(a, __shfl_xor(a, 32, 64));
        b = fminf(b, __shfl_xor(b, 16, 64)); b = fminf(b, __shfl_xor(b, 32, 64));
        if (kg == 0){
          maxb[(size_t)(qa + qs)*128 + ocb*16 + m16] = a;
          minb[(size_t)(qa + qs)*128 + ocb*16 + m16] = b;
        }
      }
  }

  #pragma unroll
  for (int ocb = 0; ocb < 8; ++ocb){
    float s = sA[ocb], q = qA[ocb];
    s += __shfl_xor(s, 16, 64); s += __shfl_xor(s, 32, 64);
    q += __shfl_xor(q, 16, 64); q += __shfl_xor(q, 32, 64);
    if (kg == 0){
      atomicAdd(&sacc[ocb*16 + m16], s);
      atomicAdd(&sacc[128 + ocb*16 + m16], q);
    }
  }
  __syncthreads();
  atomicAdd(&acc2[tid], sacc[tid]);
}

// ---------- Final: in-kernel ss2; out = relu(scale*(scale>=0?max:min)+shift); new_xyz ----------
__global__ __launch_bounds__(256) void final_kernel(const float* __restrict__ xyz,
                                                    const float* __restrict__ maxb,
                                                    const float* __restrict__ minb,
                                                    const float* __restrict__ acc2, // (256)
                                                    const float* __restrict__ g,
                                                    const float* __restrict__ be,
                                                    float* __restrict__ out){
  __shared__ float ssl[256];
  const int tid = threadIdx.x;
  if (tid < 128){
    const float invM = 1.f / (float)MROWS;
    const float mean = acc2[tid] * invM;
    const float var  = acc2[128 + tid] * invM - mean*mean;
    const float scale = g[tid] * rsqrtf(var + 1e-5f);
    ssl[2*tid + 0] = scale;
    ssl[2*tid + 1] = be[tid] - mean * scale;
  }
  __syncthreads();

  const int q = blockIdx.x * 4 + (tid >> 6);
  const int p = tid & 63;
  const float sc0 = ssl[4*p + 0], sh0 = ssl[4*p + 1];
  const float sc1 = ssl[4*p + 2], sh1 = ssl[4*p + 3];
  const float2 mxv = ((const float2*)(maxb + (size_t)q*128))[p];
  const float2 mnv = ((const float2*)(minb + (size_t)q*128))[p];
  const float h0v = (sc0 >= 0.f) ? mxv.x : mnv.x;
  const float h1v = (sc1 >= 0.f) ? mxv.y : mnv.y;
  float2 r;
  r.x = fmaxf(fmaf(sc0, h0v, sh0), 0.f);
  r.y = fmaxf(fmaf(sc1, h1v, sh1), 0.f);
  ((float2*)(out + (size_t)NB*NQ*3))[(size_t)q*64 + p] = r;
  if (p < 3){
    const int b_ = q >> 10, s = q & 1023;
    out[(size_t)q*3 + p] = xyz[((size_t)b_ * NPTS + s)*3 + p];
  }
}

// ---------- host ----------
extern "C" void kernel_launch(void* const* d_in, const int* in_sizes, int n_in,
                              void* d_out, int out_size, void* d_ws, size_t ws_size,
                              hipStream_t stream){
  (void)in_sizes; (void)n_in; (void)out_size; (void)ws_size;
  const float* xyz = (const float*)d_in[0];
  const float* pts = (const float*)d_in[1];
  const float* W0  = (const float*)d_in[2];
  const float* b0  = (const float*)d_in[3];
  const float* g0  = (const float*)d_in[4];
  const float* be0 = (const float*)d_in[5];
  const float* W1  = (const float*)d_in[6];
  const float* b1  = (const float*)d_in[7];
  const float* g1  = (const float*)d_in[8];
  const float* be1 = (const float*)d_in[9];
  const float* W2  = (const float*)d_in[10];
  const float* b2  = (const float*)d_in[11];
  const float* g2  = (const float*)d_in[12];
  const float* be2 = (const float*)d_in[13];

  // workspace: idx 2MB | acc 512f | h0 64MB | h1 64MB  (~130 MB)
  // max/min buffers (8MB each) reuse the h0 region (dead after l1).
  char* ws = (char*)d_ws;
  int*   idx = (int*)ws;
  float* acc = (float*)(ws + 2097152);
  unsigned* h0 = (unsigned*)(ws + 2101248);
  unsigned* h1 = (unsigned*)(ws + 2101248 + 67108864);
  float* maxb = (float*)h0;
  float* minb = maxb + (size_t)16384*128;
  float* out = (float*)d_out;

  float* acc0 = acc, *acc1 = acc + 128, *acc2 = acc + 256;   // acc2: 256 floats

  topk_kernel<<<1024, 512, 0, stream>>>(xyz, idx, acc);
  l0_mfma<<<2048, 256, 0, stream>>>(xyz, pts, idx, W0, b0, (unsigned short*)h0, acc0);
  l1_mfma<<<1024, 256, 0, stream>>>(h0, acc0, g0, be0, W1, b1, (unsigned short*)h1, acc1);
  l2_fused<<<1024, 256, 0, stream>>>(h1, acc1, g1, be1, W2, b2, maxb, minb, acc2);
  final_kernel<<<4096, 256, 0, stream>>>(xyz, maxb, minb, acc2, g2, be2, out);
}

// Round 9
// 270.189 us; speedup vs baseline: 1.6859x; 1.1116x over previous
//
#include <hip/hip_runtime.h>

#define NPTS 4096
#define NQ   1024     // S
#define NB   16       // B
#define KNN  32
#define MROWS 524288  // B*S*K
#define FLT_MAX_ 3.402823466e+38f

typedef __attribute__((ext_vector_type(8))) short short8;
typedef __attribute__((ext_vector_type(4))) float f32x4;

// ---------- bf16 helpers ----------
__device__ inline unsigned short f2bf(float x){
  unsigned u = __float_as_uint(x);
  u += 0x7fffu + ((u >> 16) & 1u);
  return (unsigned short)(u >> 16);
}
// HW packed f32->bf16 (RNE): low16 = cvt(lo), high16 = cvt(hi)
__device__ __forceinline__ unsigned cvt_pk_bf16(float lo, float hi){
  unsigned r;
  asm("v_cvt_pk_bf16_f32 %0, %1, %2" : "=v"(r) : "v"(lo), "v"(hi));
  return r;
}

// normalize+relu 8 bf16 (one A-fragment k-slice) -> bf16 frag, via cvt_pk
__device__ __forceinline__ short8 norm_frag(uint4 v, const float* sc, const float* sh){
  const unsigned u[4] = {v.x, v.y, v.z, v.w};
  unsigned w[4];
  #pragma unroll
  for (int t = 0; t < 4; ++t){
    float lo = __uint_as_float(u[t] << 16);
    float hi = __uint_as_float(u[t] & 0xffff0000u);
    lo = fmaxf(fmaf(lo, sc[2*t+0], sh[2*t+0]), 0.f);
    hi = fmaxf(fmaf(hi, sc[2*t+1], sh[2*t+1]), 0.f);
    w[t] = cvt_pk_bf16(lo, hi);
  }
  union { uint4 u4; short8 s8; } cv;
  cv.u4.x = w[0]; cv.u4.y = w[1]; cv.u4.z = w[2]; cv.u4.w = w[3];
  return cv.s8;
}

// sorted-insert of packed key pd into top-4 cache (c0<=c1<=c2<=c3)
__device__ __forceinline__ void ins4(double pd, double& c0, double& c1, double& c2, double& c3){
  const double t3 = fmin(c3, pd);
  const double n2 = fmin(c2, t3), x3 = fmax(c2, t3);
  const double n1 = fmin(c1, n2), x2 = fmax(c1, n2);
  const double n0 = fmin(c0, n1), x1 = fmax(c0, n1);
  c0 = n0; c1 = x1; c2 = x2; c3 = x3;
}

// rescan for ONE query with skip mask (rare path) — MUST stay inline (R6 spill lesson)
__device__ __forceinline__ void scan1(const float* xs, const float* ys, const float* zs,
                                      int lane, float qx, float qy, float qz, float src2,
                                      unsigned long long skip,
                                      double& c0, double& c1, double& c2, double& c3){
  for (int e = 0; e < 64; ++e){
    if ((skip >> e) & 1ull) continue;
    const int j = (e << 6) | lane;
    const float px = xs[j], py = ys[j], pz = zs[j];
    const float dst2 = (px*px + py*py) + pz*pz;
    const float dot  = (qx*px + qy*py) + qz*pz;
    const float d = fmaf(dot, -2.f, src2 + dst2);
    const unsigned long long uu =
        (unsigned long long)__double_as_longlong((double)d) | (unsigned)j;
    ins4(__longlong_as_double((long long)uu), c0, c1, c2, c3);
  }
}

// ---------- Kernel 1: top-K=32 NN. 512 blocks x 1024 thr (16 waves, 32 queries/block) ----------
// 2 blocks/CU = full 32-wave occupancy, zero grid tail. Wave code identical to R8.
__global__ __launch_bounds__(1024) void topk_kernel(const float* __restrict__ xyz,
                                                    int* __restrict__ idx_out,
                                                    float* __restrict__ statsacc){
  __shared__ float xs[NPTS], ys[NPTS], zs[NPTS];   // 48 KB
  const int tid = threadIdx.x;
  if (blockIdx.x == 0){
    statsacc[tid] = 0.f;
    statsacc[tid + 1024] = 0.f;
  }

  const int b = blockIdx.x >> 5;         // 32 blocks per batch, 32 queries/block
  const float* xb = xyz + (size_t)b * NPTS * 3;
  for (int p = tid; p < NPTS; p += 1024){
    xs[p] = xb[3*p + 0];
    ys[p] = xb[3*p + 1];
    zs[p] = xb[3*p + 2];
  }
  __syncthreads();

  const int wv   = tid >> 6;
  const int lane = tid & 63;
  const int qA   = blockIdx.x * 32 + wv*2;
  const int qB   = qA + 1;
  const int sA_  = qA & (NQ - 1);
  const int sB_  = qB & (NQ - 1);

  const float axq = xs[sA_], ayq = ys[sA_], azq = zs[sA_];
  const float bxq = xs[sB_], byq = ys[sB_], bzq = zs[sB_];
  const float src2A = (axq*axq + ayq*ayq) + azq*azq;
  const float src2B = (bxq*bxq + byq*byq) + bzq*bzq;

  const double DINF = __builtin_inf();
  double a0 = DINF, a1 = DINF, a2 = DINF, a3 = DINF;
  double b0 = DINF, b1 = DINF, b2 = DINF, b3 = DINF;

  for (int e = 0; e < 64; ++e){
    const int j = (e << 6) | lane;
    const float px = xs[j], py = ys[j], pz = zs[j];
    const float dst2 = (px*px + py*py) + pz*pz;
    const float dotA = (axq*px + ayq*py) + azq*pz;
    const float dotB = (bxq*px + byq*py) + bzq*pz;
    const float dA = fmaf(dotA, -2.f, src2A + dst2);
    const float dB = fmaf(dotB, -2.f, src2B + dst2);
    const unsigned long long uA =
        (unsigned long long)__double_as_longlong((double)dA) | (unsigned)j;
    const unsigned long long uB =
        (unsigned long long)__double_as_longlong((double)dB) | (unsigned)j;
    ins4(__longlong_as_double((long long)uA), a0, a1, a2, a3);
    ins4(__longlong_as_double((long long)uB), b0, b1, b2, b3);
  }

  unsigned long long skipA = 0ull, skipB = 0ull;
  int ncA = 4, ncB = 4;
  int winA = 0, winB = 0;

  #pragma unroll 1
  for (int it = 0; it < KNN; ++it){
    double wA = a0, wB = b0;
    #pragma unroll
    for (int m = 32; m >= 1; m >>= 1){
      wA = fmin(wA, __shfl_xor(wA, m, 64));
      wB = fmin(wB, __shfl_xor(wB, m, 64));
    }
    if (lane == it){
      winA = (int)((unsigned)__double_as_longlong(wA) & 0xFFFu);
      winB = (int)((unsigned)__double_as_longlong(wB) & 0xFFFu);
    }
    if (a0 == wA){
      const unsigned lo = (unsigned)__double_as_longlong(a0);
      skipA |= 1ull << ((lo >> 6) & 63u);
      a0 = a1; a1 = a2; a2 = a3; a3 = DINF;
      if (--ncA == 0){
        a0 = a1 = a2 = a3 = DINF;
        scan1(xs, ys, zs, lane, axq, ayq, azq, src2A, skipA, a0, a1, a2, a3);
        ncA = 4;
      }
    }
    if (b0 == wB){
      const unsigned lo = (unsigned)__double_as_longlong(b0);
      skipB |= 1ull << ((lo >> 6) & 63u);
      b0 = b1; b1 = b2; b2 = b3; b3 = DINF;
      if (--ncB == 0){
        b0 = b1 = b2 = b3 = DINF;
        scan1(xs, ys, zs, lane, bxq, byq, bzq, src2B, skipB, b0, b1, b2, b3);
        ncB = 4;
      }
    }
  }
  if (lane < KNN){
    idx_out[qA * KNN + lane] = winA;
    idx_out[qB * KNN + lane] = winB;
  }
}

// ---------- Layer 0: gather + concat + SWAPPED MFMA GEMM (K padded 67->96), fused stats ----------
// acc banked 4-way by blockIdx&3 (atomic fan-in reduction).
__global__ __launch_bounds__(256) void l0_mfma(const float* __restrict__ xyz,
                                               const float* __restrict__ pts,
                                               const int*   __restrict__ idxbuf,
                                               const float* __restrict__ W,     // (64,67)
                                               const float* __restrict__ bias,  // (64)
                                               unsigned short* __restrict__ hout,
                                               float* __restrict__ acc){        // 4 x 128
  __shared__ short lds[256*104];
  __shared__ float sacc[128];
  const int tid = threadIdx.x;
  if (tid < 128) sacc[tid] = 0.f;
  const int lane = tid & 63, wv = tid >> 6;
  const int m16 = lane & 15, kg = lane >> 4;

  short8 Wf[4][3];
  f32x4  bl4[4];
  for (int cg = 0; cg < 4; ++cg){
    bl4[cg] = *(const f32x4*)(bias + cg*16 + kg*4);
    const int n = cg*16 + m16;
    for (int ks = 0; ks < 3; ++ks){
      short8 t;
      #pragma unroll
      for (int i = 0; i < 8; ++i){
        const int k = ks*32 + kg*8 + i;
        float wv_ = 0.f;
        if (k < 64) wv_ = W[n*67 + 3 + k];
        else if (k < 67) wv_ = W[n*67 + (k - 64)];
        t[i] = (short)f2bf(wv_);
      }
      Wf[cg][ks] = t;
    }
  }

  {
    const int row = blockIdx.x*256 + tid;
    const int rowq = row >> 5;
    const int b = rowq >> 10, s = rowq & 1023;
    const int j = idxbuf[row];
    const float4* p4 = (const float4*)(pts + ((size_t)b*NPTS + j)*64);
    short* myrow = lds + tid*104;
    #pragma unroll
    for (int u = 0; u < 8; ++u){
      float4 x = p4[2*u], y = p4[2*u+1];
      uint4 o;
      o.x = cvt_pk_bf16(x.x, x.y);
      o.y = cvt_pk_bf16(x.z, x.w);
      o.z = cvt_pk_bf16(y.x, y.y);
      o.w = cvt_pk_bf16(y.z, y.w);
      *(uint4*)(myrow + u*8) = o;
    }
    const float* pj = xyz + ((size_t)b*NPTS + j)*3;
    const float* ps = xyz + ((size_t)b*NPTS + s)*3;
    uint4 z;
    z.x = cvt_pk_bf16(pj[0]-ps[0], pj[1]-ps[1]);
    z.y = cvt_pk_bf16(pj[2]-ps[2], 0.f);
    z.z = 0u; z.w = 0u;
    *(uint4*)(myrow + 64) = z;
    uint4 zz; zz.x = zz.y = zz.z = zz.w = 0u;
    *(uint4*)(myrow + 72) = zz;
    *(uint4*)(myrow + 80) = zz;
    *(uint4*)(myrow + 88) = zz;
  }
  __syncthreads();

  f32x4 zero4 = {0.f, 0.f, 0.f, 0.f};
  f32x4 sA[4] = {zero4, zero4, zero4, zero4};
  f32x4 qA[4] = {zero4, zero4, zero4, zero4};

  const int rowbase = blockIdx.x*256 + wv*64;
  for (int rt = 0; rt < 4; ++rt){
    const short* ar = lds + (wv*64 + rt*16 + m16)*104;
    short8 x0 = *(const short8*)(ar + kg*8);
    short8 x1 = *(const short8*)(ar + 32 + kg*8);
    short8 x2 = *(const short8*)(ar + 64 + kg*8);
    const size_t rbase = (size_t)(rowbase + rt*16 + m16) * 64;
    #pragma unroll
    for (int cg = 0; cg < 4; ++cg){
      f32x4 c = bl4[cg];
      c = __builtin_amdgcn_mfma_f32_16x16x32_bf16(Wf[cg][0], x0, c, 0, 0, 0);
      c = __builtin_amdgcn_mfma_f32_16x16x32_bf16(Wf[cg][1], x1, c, 0, 0, 0);
      c = __builtin_amdgcn_mfma_f32_16x16x32_bf16(Wf[cg][2], x2, c, 0, 0, 0);
      sA[cg] += c; qA[cg] += c*c;
      uint2 o;
      o.x = cvt_pk_bf16(c[0], c[1]);
      o.y = cvt_pk_bf16(c[2], c[3]);
      *(uint2*)(hout + rbase + cg*16 + kg*4) = o;
    }
  }
  #pragma unroll
  for (int cg = 0; cg < 4; ++cg)
    #pragma unroll
    for (int m = 1; m <= 8; m <<= 1)
      #pragma unroll
      for (int t = 0; t < 4; ++t){
        sA[cg][t] += __shfl_xor(sA[cg][t], m, 64);
        qA[cg][t] += __shfl_xor(qA[cg][t], m, 64);
      }
  if (m16 == 0){
    #pragma unroll
    for (int cg = 0; cg < 4; ++cg)
      #pragma unroll
      for (int t = 0; t < 4; ++t){
        atomicAdd(&sacc[cg*16 + kg*4 + t], sA[cg][t]);
        atomicAdd(&sacc[64 + cg*16 + kg*4 + t], qA[cg][t]);
      }
  }
  __syncthreads();
  if (tid < 128) atomicAdd(&acc[(blockIdx.x & 3)*128 + tid], sacc[tid]);
}

// ---------- Layer 1: in-kernel ss0 (4-bank sum) + norm+relu + SWAPPED MFMA 64->64 ----------
__global__ __launch_bounds__(256) void l1_mfma(const unsigned* __restrict__ hin,
                                               const float* __restrict__ acc0,  // 4 x 128
                                               const float* __restrict__ g,
                                               const float* __restrict__ be,
                                               const float* __restrict__ W,     // (64,64)
                                               const float* __restrict__ bias,  // (64)
                                               unsigned short* __restrict__ hout,
                                               float* __restrict__ acc1){       // 4 x 128
  __shared__ float ssl[128];
  __shared__ float sacc[128];
  const int tid = threadIdx.x;
  if (tid < 128) sacc[tid] = 0.f;
  if (tid < 64){
    float s = 0.f, q = 0.f;
    #pragma unroll
    for (int bnk = 0; bnk < 4; ++bnk){
      s += acc0[bnk*128 + tid];
      q += acc0[bnk*128 + 64 + tid];
    }
    const float invM = 1.f / (float)MROWS;
    const float mean = s * invM;
    const float var  = q * invM - mean*mean;
    const float scale = g[tid] * rsqrtf(var + 1e-5f);
    ssl[2*tid + 0] = scale;
    ssl[2*tid + 1] = be[tid] - mean * scale;
  }
  __syncthreads();

  const int lane = tid & 63, wv = tid >> 6;
  const int m16 = lane & 15, kg = lane >> 4;

  float scl[2][8], shf[2][8];
  #pragma unroll
  for (int s2 = 0; s2 < 2; ++s2)
    #pragma unroll
    for (int i = 0; i < 8; ++i){
      const int c = s2*32 + kg*8 + i;
      scl[s2][i] = ssl[2*c];
      shf[s2][i] = ssl[2*c + 1];
    }

  short8 Wf[4][2];
  f32x4  bl4[4];
  for (int cg = 0; cg < 4; ++cg){
    bl4[cg] = *(const f32x4*)(bias + cg*16 + kg*4);
    const int n = cg*16 + m16;
    #pragma unroll
    for (int s2 = 0; s2 < 2; ++s2){
      short8 t;
      #pragma unroll
      for (int i = 0; i < 8; ++i)
        t[i] = (short)f2bf(W[n*64 + s2*32 + kg*8 + i]);
      Wf[cg][s2] = t;
    }
  }

  f32x4 zero4 = {0.f, 0.f, 0.f, 0.f};
  f32x4 sA[4] = {zero4, zero4, zero4, zero4};
  f32x4 qA[4] = {zero4, zero4, zero4, zero4};

  for (int tt = 0; tt < 2; ++tt){
    const int rowbase = (blockIdx.x*2 + tt)*256 + wv*64;
    for (int rt = 0; rt < 4; ++rt){
      const int arow = rowbase + rt*16 + m16;
      const uint4* pr = (const uint4*)hin + (size_t)arow*8;
      uint4 v0 = pr[kg];
      uint4 v1 = pr[4 + kg];
      short8 x0 = norm_frag(v0, scl[0], shf[0]);
      short8 x1 = norm_frag(v1, scl[1], shf[1]);
      const size_t rbase = (size_t)arow * 64;
      #pragma unroll
      for (int cg = 0; cg < 4; ++cg){
        f32x4 c = bl4[cg];
        c = __builtin_amdgcn_mfma_f32_16x16x32_bf16(Wf[cg][0], x0, c, 0, 0, 0);
        c = __builtin_amdgcn_mfma_f32_16x16x32_bf16(Wf[cg][1], x1, c, 0, 0, 0);
        sA[cg] += c; qA[cg] += c*c;
        uint2 o;
        o.x = cvt_pk_bf16(c[0], c[1]);
        o.y = cvt_pk_bf16(c[2], c[3]);
        *(uint2*)(hout + rbase + cg*16 + kg*4) = o;
      }
    }
  }
  #pragma unroll
  for (int cg = 0; cg < 4; ++cg)
    #pragma unroll
    for (int m = 1; m <= 8; m <<= 1)
      #pragma unroll
      for (int t = 0; t < 4; ++t){
        sA[cg][t] += __shfl_xor(sA[cg][t], m, 64);
        qA[cg][t] += __shfl_xor(qA[cg][t], m, 64);
      }
  if (m16 == 0){
    #pragma unroll
    for (int cg = 0; cg < 4; ++cg)
      #pragma unroll
      for (int t = 0; t < 4; ++t){
        atomicAdd(&sacc[cg*16 + kg*4 + t], sA[cg][t]);
        atomicAdd(&sacc[64 + cg*16 + kg*4 + t], qA[cg][t]);
      }
  }
  __syncthreads();
  if (tid < 128) atomicAdd(&acc1[(blockIdx.x & 3)*128 + tid], sacc[tid]);
}

// ---------- Layer 2 FUSED: in-kernel ss1 (4-bank) + GEMM 64->128 + stats + per-(q,c) max/min ----------
__global__ __launch_bounds__(256) void l2_fused(const unsigned* __restrict__ hin,
                                                const float* __restrict__ acc1,  // 4 x 128
                                                const float* __restrict__ g,
                                                const float* __restrict__ be,
                                                const float* __restrict__ W,     // (128,64)
                                                const float* __restrict__ bias,  // (128)
                                                float* __restrict__ maxb,        // (16384,128)
                                                float* __restrict__ minb,        // (16384,128)
                                                float* __restrict__ acc2){       // 4 x 256
  __shared__ float ssl[128];
  __shared__ float sacc[256];
  const int tid = threadIdx.x;
  sacc[tid] = 0.f;
  if (tid < 64){
    float s = 0.f, q = 0.f;
    #pragma unroll
    for (int bnk = 0; bnk < 4; ++bnk){
      s += acc1[bnk*128 + tid];
      q += acc1[bnk*128 + 64 + tid];
    }
    const float invM = 1.f / (float)MROWS;
    const float mean = s * invM;
    const float var  = q * invM - mean*mean;
    const float scale = g[tid] * rsqrtf(var + 1e-5f);
    ssl[2*tid + 0] = scale;
    ssl[2*tid + 1] = be[tid] - mean * scale;
  }
  __syncthreads();

  const int lane = tid & 63, wv = tid >> 6;
  const int m16 = lane & 15, kg = lane >> 4;

  float scl[2][8], shf[2][8];
  #pragma unroll
  for (int s2 = 0; s2 < 2; ++s2)
    #pragma unroll
    for (int i = 0; i < 8; ++i){
      const int c = s2*32 + kg*8 + i;
      scl[s2][i] = ssl[2*c];
      shf[s2][i] = ssl[2*c + 1];
    }

  short8 Bf[8][2];
  float  bl[8];
  for (int ocb = 0; ocb < 8; ++ocb){
    const int n = ocb*16 + m16;
    bl[ocb] = bias[n];
    #pragma unroll
    for (int s2 = 0; s2 < 2; ++s2){
      short8 t;
      #pragma unroll
      for (int i = 0; i < 8; ++i)
        t[i] = (short)f2bf(W[n*64 + s2*32 + kg*8 + i]);
      Bf[ocb][s2] = t;
    }
  }

  float sA[8], qA[8];
  #pragma unroll
  for (int o = 0; o < 8; ++o){ sA[o] = 0.f; qA[o] = 0.f; }

  for (int tt = 0; tt < 2; ++tt){
    const int rowbase = (blockIdx.x*2 + tt)*256 + wv*64;   // 2 queries per wave
    float mx[2][8], mn[2][8];
    #pragma unroll
    for (int o = 0; o < 8; ++o){
      mx[0][o] = -FLT_MAX_; mx[1][o] = -FLT_MAX_;
      mn[0][o] =  FLT_MAX_; mn[1][o] =  FLT_MAX_;
    }
    #pragma unroll
    for (int rt = 0; rt < 4; ++rt){
      const int qs = rt >> 1;
      const int arow = rowbase + rt*16 + m16;
      const uint4* pr = (const uint4*)hin + (size_t)arow*8;
      uint4 v0 = pr[kg];
      uint4 v1 = pr[4 + kg];
      short8 a0 = norm_frag(v0, scl[0], shf[0]);
      short8 a1 = norm_frag(v1, scl[1], shf[1]);
      #pragma unroll
      for (int ocb = 0; ocb < 8; ++ocb){
        f32x4 c = {bl[ocb], bl[ocb], bl[ocb], bl[ocb]};
        c = __builtin_amdgcn_mfma_f32_16x16x32_bf16(a0, Bf[ocb][0], c, 0, 0, 0);
        c = __builtin_amdgcn_mfma_f32_16x16x32_bf16(a1, Bf[ocb][1], c, 0, 0, 0);
        #pragma unroll
        for (int r = 0; r < 4; ++r){
          const float hv = c[r];
          sA[ocb] += hv; qA[ocb] += hv*hv;
          mx[qs][ocb] = fmaxf(mx[qs][ocb], hv);
          mn[qs][ocb] = fminf(mn[qs][ocb], hv);
        }
      }
    }
    const int qa = rowbase >> 5;
    #pragma unroll
    for (int qs = 0; qs < 2; ++qs)
      #pragma unroll
      for (int ocb = 0; ocb < 8; ++ocb){
        float a = mx[qs][ocb], b = mn[qs][ocb];
        a = fmaxf(a, __shfl_xor(a, 16, 64)); a = fmaxf(a, __shfl_xor(a, 32, 64));
        b = fminf(b, __shfl_xor(b, 16, 64)); b = fminf(b, __shfl_xor(b, 32, 64));
        if (kg == 0){
          maxb[(size_t)(qa + qs)*128 + ocb*16 + m16] = a;
          minb[(size_t)(qa + qs)*128 + ocb*16 + m16] = b;
        }
      }
  }

  #pragma unroll
  for (int ocb = 0; ocb < 8; ++ocb){
    float s = sA[ocb], q = qA[ocb];
    s += __shfl_xor(s, 16, 64); s += __shfl_xor(s, 32, 64);
    q += __shfl_xor(q, 16, 64); q += __shfl_xor(q, 32, 64);
    if (kg == 0){
      atomicAdd(&sacc[ocb*16 + m16], s);
      atomicAdd(&sacc[128 + ocb*16 + m16], q);
    }
  }
  __syncthreads();
  atomicAdd(&acc2[(blockIdx.x & 3)*256 + tid], sacc[tid]);
}

// ---------- Final: in-kernel ss2 (4-bank); out = relu(scale*(scale>=0?max:min)+shift) ----------
__global__ __launch_bounds__(256) void final_kernel(const float* __restrict__ xyz,
                                                    const float* __restrict__ maxb,
                                                    const float* __restrict__ minb,
                                                    const float* __restrict__ acc2, // 4 x 256
                                                    const float* __restrict__ g,
                                                    const float* __restrict__ be,
                                                    float* __restrict__ out){
  __shared__ float ssl[256];
  const int tid = threadIdx.x;
  if (tid < 128){
    float s = 0.f, q = 0.f;
    #pragma unroll
    for (int bnk = 0; bnk < 4; ++bnk){
      s += acc2[bnk*256 + tid];
      q += acc2[bnk*256 + 128 + tid];
    }
    const float invM = 1.f / (float)MROWS;
    const float mean = s * invM;
    const float var  = q * invM - mean*mean;
    const float scale = g[tid] * rsqrtf(var + 1e-5f);
    ssl[2*tid + 0] = scale;
    ssl[2*tid + 1] = be[tid] - mean * scale;
  }
  __syncthreads();

  const int q = blockIdx.x * 4 + (tid >> 6);
  const int p = tid & 63;
  const float sc0 = ssl[4*p + 0], sh0 = ssl[4*p + 1];
  const float sc1 = ssl[4*p + 2], sh1 = ssl[4*p + 3];
  const float2 mxv = ((const float2*)(maxb + (size_t)q*128))[p];
  const float2 mnv = ((const float2*)(minb + (size_t)q*128))[p];
  const float h0v = (sc0 >= 0.f) ? mxv.x : mnv.x;
  const float h1v = (sc1 >= 0.f) ? mxv.y : mnv.y;
  float2 r;
  r.x = fmaxf(fmaf(sc0, h0v, sh0), 0.f);
  r.y = fmaxf(fmaf(sc1, h1v, sh1), 0.f);
  ((float2*)(out + (size_t)NB*NQ*3))[(size_t)q*64 + p] = r;
  if (p < 3){
    const int b_ = q >> 10, s = q & 1023;
    out[(size_t)q*3 + p] = xyz[((size_t)b_ * NPTS + s)*3 + p];
  }
}

// ---------- host ----------
extern "C" void kernel_launch(void* const* d_in, const int* in_sizes, int n_in,
                              void* d_out, int out_size, void* d_ws, size_t ws_size,
                              hipStream_t stream){
  (void)in_sizes; (void)n_in; (void)out_size; (void)ws_size;
  const float* xyz = (const float*)d_in[0];
  const float* pts = (const float*)d_in[1];
  const float* W0  = (const float*)d_in[2];
  const float* b0  = (const float*)d_in[3];
  const float* g0  = (const float*)d_in[4];
  const float* be0 = (const float*)d_in[5];
  const float* W1  = (const float*)d_in[6];
  const float* b1  = (const float*)d_in[7];
  const float* g1  = (const float*)d_in[8];
  const float* be1 = (const float*)d_in[9];
  const float* W2  = (const float*)d_in[10];
  const float* b2  = (const float*)d_in[11];
  const float* g2  = (const float*)d_in[12];
  const float* be2 = (const float*)d_in[13];

  // workspace: idx 2MB | acc 2048f (acc0 4x128 | acc1 4x128 | acc2 4x256) | h0 64MB | h1 64MB
  char* ws = (char*)d_ws;
  int*   idx = (int*)ws;
  float* acc = (float*)(ws + 2097152);
  unsigned* h0 = (unsigned*)(ws + 2097152 + 8192);
  unsigned* h1 = (unsigned*)(ws + 2097152 + 8192 + 67108864);
  float* maxb = (float*)h0;                    // reuses h0 (dead after l1)
  float* minb = maxb + (size_t)16384*128;
  float* out = (float*)d_out;

  float* acc0 = acc, *acc1 = acc + 512, *acc2 = acc + 1024;

  topk_kernel<<<512, 1024, 0, stream>>>(xyz, idx, acc);
  l0_mfma<<<2048, 256, 0, stream>>>(xyz, pts, idx, W0, b0, (unsigned short*)h0, acc0);
  l1_mfma<<<1024, 256, 0, stream>>>(h0, acc0, g0, be0, W1, b1, (unsigned short*)h1, acc1);
  l2_fused<<<1024, 256, 0, stream>>>(h1, acc1, g1, be1, W2, b2, maxb, minb, acc2);
  final_kernel<<<4096, 256, 0, stream>>>(xyz, maxb, minb, acc2, g2, be2, out);
}

// Round 10
// 243.998 us; speedup vs baseline: 1.8669x; 1.1073x over previous
//
#include <hip/hip_runtime.h>

#define NPTS 4096
#define NQ   1024     // S
#define NB   16       // B
#define KNN  32
#define MROWS 524288  // B*S*K
#define FLT_MAX_ 3.402823466e+38f

typedef __attribute__((ext_vector_type(8))) short short8;
typedef __attribute__((ext_vector_type(4))) float f32x4;

// ---------- bf16 helpers ----------
__device__ inline unsigned short f2bf(float x){
  unsigned u = __float_as_uint(x);
  u += 0x7fffu + ((u >> 16) & 1u);
  return (unsigned short)(u >> 16);
}
__device__ __forceinline__ unsigned cvt_pk_bf16(float lo, float hi){
  unsigned r;
  asm("v_cvt_pk_bf16_f32 %0, %1, %2" : "=v"(r) : "v"(lo), "v"(hi));
  return r;
}

// normalize+relu 8 bf16 (one A-fragment k-slice) -> bf16 frag, via cvt_pk
__device__ __forceinline__ short8 norm_frag(uint4 v, const float* sc, const float* sh){
  const unsigned u[4] = {v.x, v.y, v.z, v.w};
  unsigned w[4];
  #pragma unroll
  for (int t = 0; t < 4; ++t){
    float lo = __uint_as_float(u[t] << 16);
    float hi = __uint_as_float(u[t] & 0xffff0000u);
    lo = fmaxf(fmaf(lo, sc[2*t+0], sh[2*t+0]), 0.f);
    hi = fmaxf(fmaf(hi, sc[2*t+1], sh[2*t+1]), 0.f);
    w[t] = cvt_pk_bf16(lo, hi);
  }
  union { uint4 u4; short8 s8; } cv;
  cv.u4.x = w[0]; cv.u4.y = w[1]; cv.u4.z = w[2]; cv.u4.w = w[3];
  return cv.s8;
}

// sorted-insert of packed key pd into top-5 cache (c0<=..<=c4)
__device__ __forceinline__ void ins5(double pd, double& c0, double& c1, double& c2,
                                     double& c3, double& c4){
  const double t4 = fmin(c4, pd);
  const double n3 = fmin(c3, t4), x4 = fmax(c3, t4);
  const double n2 = fmin(c2, n3), x3 = fmax(c2, n3);
  const double n1 = fmin(c1, n2), x2 = fmax(c1, n2);
  const double n0 = fmin(c0, n1), x1 = fmax(c0, n1);
  c0 = n0; c1 = x1; c2 = x2; c3 = x3; c4 = x4;
}

// rescan ONE query with chunk-skip mask (rare path) — inline (R6 spill lesson)
__device__ __forceinline__ void scan5(const float* xs, const float* ys, const float* zs,
                                      const float* ws2, int lane,
                                      float qx, float qy, float qz, float src2,
                                      unsigned long long skip,
                                      double& c0, double& c1, double& c2, double& c3, double& c4){
  for (int e = 0; e < 64; ++e){
    if ((skip >> e) & 1ull) continue;
    const int j = (e << 6) | lane;
    const float px = xs[j], py = ys[j], pz = zs[j];
    const float dot = (qx*px + qy*py) + qz*pz;
    const float d = fmaf(dot, -2.f, src2 + ws2[j]);
    const unsigned long long uu =
        (unsigned long long)__double_as_longlong((double)d) | (unsigned)j;
    ins5(__longlong_as_double((long long)uu), c0, c1, c2, c3, c4);
  }
}

// proven iterative extractor (R9 path, 5-deep) — fallback only
__device__ __forceinline__ void extract_old(const float* xs, const float* ys, const float* zs,
                                            const float* ws2, int lane,
                                            float qx, float qy, float qz, float src2,
                                            int qidx, int* idx_out,
                                            double c0, double c1, double c2, double c3, double c4){
  const double DINF = __builtin_inf();
  unsigned long long skip = 0ull;
  int nc = 5;
  int win = 0;
  #pragma unroll 1
  for (int it = 0; it < KNN; ++it){
    double w = c0;
    #pragma unroll
    for (int m = 32; m >= 1; m >>= 1)
      w = fmin(w, __shfl_xor(w, m, 64));
    if (lane == it) win = (int)((unsigned)__double_as_longlong(w) & 0xFFFu);
    if (c0 == w){
      const unsigned lo = (unsigned)__double_as_longlong(c0);
      skip |= 1ull << ((lo >> 6) & 63u);
      c0 = c1; c1 = c2; c2 = c3; c3 = c4; c4 = DINF;
      if (--nc == 0){
        c0 = c1 = c2 = c3 = c4 = DINF;
        scan5(xs, ys, zs, ws2, lane, qx, qy, qz, src2, skip, c0, c1, c2, c3, c4);
        nc = 5;
      }
    }
  }
  if (lane < KNN) idx_out[qidx * KNN + lane] = win;
}

// ---------- Kernel 1: top-K=32 NN set via per-lane top-5 + threshold bisection ----------
// Winners are emitted UNORDERED (downstream is permutation-invariant over k).
__global__ __launch_bounds__(1024) void topk_kernel(const float* __restrict__ xyz,
                                                    int* __restrict__ idx_out,
                                                    float* __restrict__ statsacc){
  __shared__ float xs[NPTS], ys[NPTS], zs[NPTS], ws2[NPTS];   // 64 KB
  const int tid = threadIdx.x;
  if (blockIdx.x == 0){
    statsacc[tid] = 0.f;
    statsacc[tid + 1024] = 0.f;
  }

  const int b = blockIdx.x >> 5;         // 32 blocks per batch, 32 queries/block
  const float* xb = xyz + (size_t)b * NPTS * 3;
  for (int p = tid; p < NPTS; p += 1024){
    const float x = xb[3*p + 0], y = xb[3*p + 1], z = xb[3*p + 2];
    xs[p] = x; ys[p] = y; zs[p] = z;
    ws2[p] = (x*x + y*y) + z*z;
  }
  __syncthreads();

  const int wv   = tid >> 6;
  const int lane = tid & 63;
  const int qA   = blockIdx.x * 32 + wv*2;
  const int qB   = qA + 1;
  const int sA_  = qA & (NQ - 1);
  const int sB_  = qB & (NQ - 1);

  const float axq = xs[sA_], ayq = ys[sA_], azq = zs[sA_];
  const float bxq = xs[sB_], byq = ys[sB_], bzq = zs[sB_];
  const float src2A = ws2[sA_];
  const float src2B = ws2[sB_];

  const double DINF = __builtin_inf();
  double a0 = DINF, a1 = DINF, a2 = DINF, a3 = DINF, a4 = DINF;
  double b0 = DINF, b1 = DINF, b2 = DINF, b3 = DINF, b4 = DINF;

  // init scan: shared point loads, dual independent top-5 insert chains
  for (int e = 0; e < 64; ++e){
    const int j = (e << 6) | lane;
    const float px = xs[j], py = ys[j], pz = zs[j];
    const float dst2 = ws2[j];
    const float dotA = (axq*px + ayq*py) + azq*pz;
    const float dotB = (bxq*px + byq*py) + bzq*pz;
    const float dA = fmaf(dotA, -2.f, src2A + dst2);
    const float dB = fmaf(dotB, -2.f, src2B + dst2);
    const unsigned long long uA =
        (unsigned long long)__double_as_longlong((double)dA) | (unsigned)j;
    const unsigned long long uB =
        (unsigned long long)__double_as_longlong((double)dB) | (unsigned)j;
    ins5(__longlong_as_double((long long)uA), a0, a1, a2, a3, a4);
    ins5(__longlong_as_double((long long)uB), b0, b1, b2, b3, b4);
  }

  // threshold bisection: find T with |{key < T}| == 32 (keys unique by construction)
  double loA = -1024.0, hiA = 1024.0, TA = 0.0;
  double loB = -1024.0, hiB = 1024.0, TB = 0.0;
  bool doneA = false, doneB = false;
  #pragma unroll 1
  for (int bi = 0; bi < 64 && !(doneA && doneB); ++bi){
    if (!doneA){
      const double g = 0.5*loA + 0.5*hiA;
      const int cnt = __popcll(__ballot(a0 < g)) + __popcll(__ballot(a1 < g))
                    + __popcll(__ballot(a2 < g)) + __popcll(__ballot(a3 < g))
                    + __popcll(__ballot(a4 < g));
      if (cnt >= KNN){ hiA = g; if (cnt == KNN){ TA = g; doneA = true; } }
      else loA = g;
    }
    if (!doneB){
      const double g = 0.5*loB + 0.5*hiB;
      const int cnt = __popcll(__ballot(b0 < g)) + __popcll(__ballot(b1 < g))
                    + __popcll(__ballot(b2 < g)) + __popcll(__ballot(b3 < g))
                    + __popcll(__ballot(b4 < g));
      if (cnt >= KNN){ hiB = g; if (cnt == KNN){ TB = g; doneB = true; } }
      else loB = g;
    }
  }

  const unsigned long long below = (1ull << lane) - 1ull;

  // query A: emit set if valid (no lane exhausted its cache), else exact fallback
  if (doneA && !__any(a4 < TA)){
    const unsigned long long m0 = __ballot(a0 < TA);
    const unsigned long long m1 = __ballot(a1 < TA);
    const unsigned long long m2 = __ballot(a2 < TA);
    const unsigned long long m3 = __ballot(a3 < TA);
    const int p0 = __popcll(m0), p1 = p0 + __popcll(m1), p2 = p1 + __popcll(m2);
    int* outq = idx_out + qA * KNN;
    if (a0 < TA) outq[__popcll(m0 & below)]      = (int)((unsigned)__double_as_longlong(a0) & 0xFFFu);
    if (a1 < TA) outq[p0 + __popcll(m1 & below)] = (int)((unsigned)__double_as_longlong(a1) & 0xFFFu);
    if (a2 < TA) outq[p1 + __popcll(m2 & below)] = (int)((unsigned)__double_as_longlong(a2) & 0xFFFu);
    if (a3 < TA) outq[p2 + __popcll(m3 & below)] = (int)((unsigned)__double_as_longlong(a3) & 0xFFFu);
  } else {
    extract_old(xs, ys, zs, ws2, lane, axq, ayq, azq, src2A, qA, idx_out, a0, a1, a2, a3, a4);
  }

  // query B
  if (doneB && !__any(b4 < TB)){
    const unsigned long long m0 = __ballot(b0 < TB);
    const unsigned long long m1 = __ballot(b1 < TB);
    const unsigned long long m2 = __ballot(b2 < TB);
    const unsigned long long m3 = __ballot(b3 < TB);
    const int p0 = __popcll(m0), p1 = p0 + __popcll(m1), p2 = p1 + __popcll(m2);
    int* outq = idx_out + qB * KNN;
    if (b0 < TB) outq[__popcll(m0 & below)]      = (int)((unsigned)__double_as_longlong(b0) & 0xFFFu);
    if (b1 < TB) outq[p0 + __popcll(m1 & below)] = (int)((unsigned)__double_as_longlong(b1) & 0xFFFu);
    if (b2 < TB) outq[p1 + __popcll(m2 & below)] = (int)((unsigned)__double_as_longlong(b2) & 0xFFFu);
    if (b3 < TB) outq[p2 + __popcll(m3 & below)] = (int)((unsigned)__double_as_longlong(b3) & 0xFFFu);
  } else {
    extract_old(xs, ys, zs, ws2, lane, bxq, byq, bzq, src2B, qB, idx_out, b0, b1, b2, b3, b4);
  }
}

// ---------- Layer 0: gather + concat + SWAPPED MFMA GEMM (K padded 67->96), fused stats ----------
__global__ __launch_bounds__(256) void l0_mfma(const float* __restrict__ xyz,
                                               const float* __restrict__ pts,
                                               const int*   __restrict__ idxbuf,
                                               const float* __restrict__ W,     // (64,67)
                                               const float* __restrict__ bias,  // (64)
                                               unsigned short* __restrict__ hout,
                                               float* __restrict__ acc){        // 4 x 128
  __shared__ short lds[256*104];
  __shared__ float sacc[128];
  const int tid = threadIdx.x;
  if (tid < 128) sacc[tid] = 0.f;
  const int lane = tid & 63, wv = tid >> 6;
  const int m16 = lane & 15, kg = lane >> 4;

  short8 Wf[4][3];
  f32x4  bl4[4];
  for (int cg = 0; cg < 4; ++cg){
    bl4[cg] = *(const f32x4*)(bias + cg*16 + kg*4);
    const int n = cg*16 + m16;
    for (int ks = 0; ks < 3; ++ks){
      short8 t;
      #pragma unroll
      for (int i = 0; i < 8; ++i){
        const int k = ks*32 + kg*8 + i;
        float wv_ = 0.f;
        if (k < 64) wv_ = W[n*67 + 3 + k];
        else if (k < 67) wv_ = W[n*67 + (k - 64)];
        t[i] = (short)f2bf(wv_);
      }
      Wf[cg][ks] = t;
    }
  }

  {
    const int row = blockIdx.x*256 + tid;
    const int rowq = row >> 5;
    const int b = rowq >> 10, s = rowq & 1023;
    const int j = idxbuf[row];
    const float4* p4 = (const float4*)(pts + ((size_t)b*NPTS + j)*64);
    short* myrow = lds + tid*104;
    #pragma unroll
    for (int u = 0; u < 8; ++u){
      float4 x = p4[2*u], y = p4[2*u+1];
      uint4 o;
      o.x = cvt_pk_bf16(x.x, x.y);
      o.y = cvt_pk_bf16(x.z, x.w);
      o.z = cvt_pk_bf16(y.x, y.y);
      o.w = cvt_pk_bf16(y.z, y.w);
      *(uint4*)(myrow + u*8) = o;
    }
    const float* pj = xyz + ((size_t)b*NPTS + j)*3;
    const float* ps = xyz + ((size_t)b*NPTS + s)*3;
    uint4 z;
    z.x = cvt_pk_bf16(pj[0]-ps[0], pj[1]-ps[1]);
    z.y = cvt_pk_bf16(pj[2]-ps[2], 0.f);
    z.z = 0u; z.w = 0u;
    *(uint4*)(myrow + 64) = z;
    uint4 zz; zz.x = zz.y = zz.z = zz.w = 0u;
    *(uint4*)(myrow + 72) = zz;
    *(uint4*)(myrow + 80) = zz;
    *(uint4*)(myrow + 88) = zz;
  }
  __syncthreads();

  f32x4 zero4 = {0.f, 0.f, 0.f, 0.f};
  f32x4 sA[4] = {zero4, zero4, zero4, zero4};
  f32x4 qA[4] = {zero4, zero4, zero4, zero4};

  const int rowbase = blockIdx.x*256 + wv*64;
  for (int rt = 0; rt < 4; ++rt){
    const short* ar = lds + (wv*64 + rt*16 + m16)*104;
    short8 x0 = *(const short8*)(ar + kg*8);
    short8 x1 = *(const short8*)(ar + 32 + kg*8);
    short8 x2 = *(const short8*)(ar + 64 + kg*8);
    const size_t rbase = (size_t)(rowbase + rt*16 + m16) * 64;
    #pragma unroll
    for (int cg = 0; cg < 4; ++cg){
      f32x4 c = bl4[cg];
      c = __builtin_amdgcn_mfma_f32_16x16x32_bf16(Wf[cg][0], x0, c, 0, 0, 0);
      c = __builtin_amdgcn_mfma_f32_16x16x32_bf16(Wf[cg][1], x1, c, 0, 0, 0);
      c = __builtin_amdgcn_mfma_f32_16x16x32_bf16(Wf[cg][2], x2, c, 0, 0, 0);
      sA[cg] += c; qA[cg] += c*c;
      uint2 o;
      o.x = cvt_pk_bf16(c[0], c[1]);
      o.y = cvt_pk_bf16(c[2], c[3]);
      *(uint2*)(hout + rbase + cg*16 + kg*4) = o;
    }
  }
  #pragma unroll
  for (int cg = 0; cg < 4; ++cg)
    #pragma unroll
    for (int m = 1; m <= 8; m <<= 1)
      #pragma unroll
      for (int t = 0; t < 4; ++t){
        sA[cg][t] += __shfl_xor(sA[cg][t], m, 64);
        qA[cg][t] += __shfl_xor(qA[cg][t], m, 64);
      }
  if (m16 == 0){
    #pragma unroll
    for (int cg = 0; cg < 4; ++cg)
      #pragma unroll
      for (int t = 0; t < 4; ++t){
        atomicAdd(&sacc[cg*16 + kg*4 + t], sA[cg][t]);
        atomicAdd(&sacc[64 + cg*16 + kg*4 + t], qA[cg][t]);
      }
  }
  __syncthreads();
  if (tid < 128) atomicAdd(&acc[(blockIdx.x & 3)*128 + tid], sacc[tid]);
}

// ---------- Layer 1: in-kernel ss0 (4-bank sum) + norm+relu + SWAPPED MFMA 64->64 ----------
__global__ __launch_bounds__(256) void l1_mfma(const unsigned* __restrict__ hin,
                                               const float* __restrict__ acc0,  // 4 x 128
                                               const float* __restrict__ g,
                                               const float* __restrict__ be,
                                               const float* __restrict__ W,     // (64,64)
                                               const float* __restrict__ bias,  // (64)
                                               unsigned short* __restrict__ hout,
                                               float* __restrict__ acc1){       // 4 x 128
  __shared__ float ssl[128];
  __shared__ float sacc[128];
  const int tid = threadIdx.x;
  if (tid < 128) sacc[tid] = 0.f;
  if (tid < 64){
    float s = 0.f, q = 0.f;
    #pragma unroll
    for (int bnk = 0; bnk < 4; ++bnk){
      s += acc0[bnk*128 + tid];
      q += acc0[bnk*128 + 64 + tid];
    }
    const float invM = 1.f / (float)MROWS;
    const float mean = s * invM;
    const float var  = q * invM - mean*mean;
    const float scale = g[tid] * rsqrtf(var + 1e-5f);
    ssl[2*tid + 0] = scale;
    ssl[2*tid + 1] = be[tid] - mean * scale;
  }
  __syncthreads();

  const int lane = tid & 63, wv = tid >> 6;
  const int m16 = lane & 15, kg = lane >> 4;

  float scl[2][8], shf[2][8];
  #pragma unroll
  for (int s2 = 0; s2 < 2; ++s2)
    #pragma unroll
    for (int i = 0; i < 8; ++i){
      const int c = s2*32 + kg*8 + i;
      scl[s2][i] = ssl[2*c];
      shf[s2][i] = ssl[2*c + 1];
    }

  short8 Wf[4][2];
  f32x4  bl4[4];
  for (int cg = 0; cg < 4; ++cg){
    bl4[cg] = *(const f32x4*)(bias + cg*16 + kg*4);
    const int n = cg*16 + m16;
    #pragma unroll
    for (int s2 = 0; s2 < 2; ++s2){
      short8 t;
      #pragma unroll
      for (int i = 0; i < 8; ++i)
        t[i] = (short)f2bf(W[n*64 + s2*32 + kg*8 + i]);
      Wf[cg][s2] = t;
    }
  }

  f32x4 zero4 = {0.f, 0.f, 0.f, 0.f};
  f32x4 sA[4] = {zero4, zero4, zero4, zero4};
  f32x4 qA[4] = {zero4, zero4, zero4, zero4};

  for (int tt = 0; tt < 2; ++tt){
    const int rowbase = (blockIdx.x*2 + tt)*256 + wv*64;
    for (int rt = 0; rt < 4; ++rt){
      const int arow = rowbase + rt*16 + m16;
      const uint4* pr = (const uint4*)hin + (size_t)arow*8;
      uint4 v0 = pr[kg];
      uint4 v1 = pr[4 + kg];
      short8 x0 = norm_frag(v0, scl[0], shf[0]);
      short8 x1 = norm_frag(v1, scl[1], shf[1]);
      const size_t rbase = (size_t)arow * 64;
      #pragma unroll
      for (int cg = 0; cg < 4; ++cg){
        f32x4 c = bl4[cg];
        c = __builtin_amdgcn_mfma_f32_16x16x32_bf16(Wf[cg][0], x0, c, 0, 0, 0);
        c = __builtin_amdgcn_mfma_f32_16x16x32_bf16(Wf[cg][1], x1, c, 0, 0, 0);
        sA[cg] += c; qA[cg] += c*c;
        uint2 o;
        o.x = cvt_pk_bf16(c[0], c[1]);
        o.y = cvt_pk_bf16(c[2], c[3]);
        *(uint2*)(hout + rbase + cg*16 + kg*4) = o;
      }
    }
  }
  #pragma unroll
  for (int cg = 0; cg < 4; ++cg)
    #pragma unroll
    for (int m = 1; m <= 8; m <<= 1)
      #pragma unroll
      for (int t = 0; t < 4; ++t){
        sA[cg][t] += __shfl_xor(sA[cg][t], m, 64);
        qA[cg][t] += __shfl_xor(qA[cg][t], m, 64);
      }
  if (m16 == 0){
    #pragma unroll
    for (int cg = 0; cg < 4; ++cg)
      #pragma unroll
      for (int t = 0; t < 4; ++t){
        atomicAdd(&sacc[cg*16 + kg*4 + t], sA[cg][t]);
        atomicAdd(&sacc[64 + cg*16 + kg*4 + t], qA[cg][t]);
      }
  }
  __syncthreads();
  if (tid < 128) atomicAdd(&acc1[(blockIdx.x & 3)*128 + tid], sacc[tid]);
}

// ---------- Layer 2 FUSED: in-kernel ss1 (4-bank) + GEMM 64->128 + stats + per-(q,c) max/min ----------
__global__ __launch_bounds__(256) void l2_fused(const unsigned* __restrict__ hin,
                                                const float* __restrict__ acc1,  // 4 x 128
                                                const float* __restrict__ g,
                                                const float* __restrict__ be,
                                                const float* __restrict__ W,     // (128,64)
                                                const float* __restrict__ bias,  // (128)
                                                float* __restrict__ maxb,        // (16384,128)
                                                float* __restrict__ minb,        // (16384,128)
                                                float* __restrict__ acc2){       // 4 x 256
  __shared__ float ssl[128];
  __shared__ float sacc[256];
  const int tid = threadIdx.x;
  sacc[tid] = 0.f;
  if (tid < 64){
    float s = 0.f, q = 0.f;
    #pragma unroll
    for (int bnk = 0; bnk < 4; ++bnk){
      s += acc1[bnk*128 + tid];
      q += acc1[bnk*128 + 64 + tid];
    }
    const float invM = 1.f / (float)MROWS;
    const float mean = s * invM;
    const float var  = q * invM - mean*mean;
    const float scale = g[tid] * rsqrtf(var + 1e-5f);
    ssl[2*tid + 0] = scale;
    ssl[2*tid + 1] = be[tid] - mean * scale;
  }
  __syncthreads();

  const int lane = tid & 63, wv = tid >> 6;
  const int m16 = lane & 15, kg = lane >> 4;

  float scl[2][8], shf[2][8];
  #pragma unroll
  for (int s2 = 0; s2 < 2; ++s2)
    #pragma unroll
    for (int i = 0; i < 8; ++i){
      const int c = s2*32 + kg*8 + i;
      scl[s2][i] = ssl[2*c];
      shf[s2][i] = ssl[2*c + 1];
    }

  short8 Bf[8][2];
  float  bl[8];
  for (int ocb = 0; ocb < 8; ++ocb){
    const int n = ocb*16 + m16;
    bl[ocb] = bias[n];
    #pragma unroll
    for (int s2 = 0; s2 < 2; ++s2){
      short8 t;
      #pragma unroll
      for (int i = 0; i < 8; ++i)
        t[i] = (short)f2bf(W[n*64 + s2*32 + kg*8 + i]);
      Bf[ocb][s2] = t;
    }
  }

  float sA[8], qA[8];
  #pragma unroll
  for (int o = 0; o < 8; ++o){ sA[o] = 0.f; qA[o] = 0.f; }

  for (int tt = 0; tt < 2; ++tt){
    const int rowbase = (blockIdx.x*2 + tt)*256 + wv*64;   // 2 queries per wave
    float mx[2][8], mn[2][8];
    #pragma unroll
    for (int o = 0; o < 8; ++o){
      mx[0][o] = -FLT_MAX_; mx[1][o] = -FLT_MAX_;
      mn[0][o] =  FLT_MAX_; mn[1][o] =  FLT_MAX_;
    }
    #pragma unroll
    for (int rt = 0; rt < 4; ++rt){
      const int qs = rt >> 1;
      const int arow = rowbase + rt*16 + m16;
      const uint4* pr = (const uint4*)hin + (size_t)arow*8;
      uint4 v0 = pr[kg];
      uint4 v1 = pr[4 + kg];
      short8 a0 = norm_frag(v0, scl[0], shf[0]);
      short8 a1 = norm_frag(v1, scl[1], shf[1]);
      #pragma unroll
      for (int ocb = 0; ocb < 8; ++ocb){
        f32x4 c = {bl[ocb], bl[ocb], bl[ocb], bl[ocb]};
        c = __builtin_amdgcn_mfma_f32_16x16x32_bf16(a0, Bf[ocb][0], c, 0, 0, 0);
        c = __builtin_amdgcn_mfma_f32_16x16x32_bf16(a1, Bf[ocb][1], c, 0, 0, 0);
        #pragma unroll
        for (int r = 0; r < 4; ++r){
          const float hv = c[r];
          sA[ocb] += hv; qA[ocb] += hv*hv;
          mx[qs][ocb] = fmaxf(mx[qs][ocb], hv);
          mn[qs][ocb] = fminf(mn[qs][ocb], hv);
        }
      }
    }
    const int qa = rowbase >> 5;
    #pragma unroll
    for (int qs = 0; qs < 2; ++qs)
      #pragma unroll
      for (int ocb = 0; ocb < 8; ++ocb){
        float a = mx[qs][ocb], b = mn[qs][ocb];
        a = fmaxf(a, __shfl_xor(a, 16, 64)); a = fmaxf(a, __shfl_xor(a, 32, 64));
        b = fminf(b, __shfl_xor(b, 16, 64)); b = fminf(b, __shfl_xor(b, 32, 64));
        if (kg == 0){
          maxb[(size_t)(qa + qs)*128 + ocb*16 + m16] = a;
          minb[(size_t)(qa + qs)*128 + ocb*16 + m16] = b;
        }
      }
  }

  #pragma unroll
  for (int ocb = 0; ocb < 8; ++ocb){
    float s = sA[ocb], q = qA[ocb];
    s += __shfl_xor(s, 16, 64); s += __shfl_xor(s, 32, 64);
    q += __shfl_xor(q, 16, 64); q += __shfl_xor(q, 32, 64);
    if (kg == 0){
      atomicAdd(&sacc[ocb*16 + m16], s);
      atomicAdd(&sacc[128 + ocb*16 + m16], q);
    }
  }
  __syncthreads();
  atomicAdd(&acc2[(blockIdx.x & 3)*256 + tid], sacc[tid]);
}

// ---------- Final: in-kernel ss2 (4-bank); out = relu(scale*(scale>=0?max:min)+shift) ----------
__global__ __launch_bounds__(256) void final_kernel(const float* __restrict__ xyz,
                                                    const float* __restrict__ maxb,
                                                    const float* __restrict__ minb,
                                                    const float* __restrict__ acc2, // 4 x 256
                                                    const float* __restrict__ g,
                                                    const float* __restrict__ be,
                                                    float* __restrict__ out){
  __shared__ float ssl[256];
  const int tid = threadIdx.x;
  if (tid < 128){
    float s = 0.f, q = 0.f;
    #pragma unroll
    for (int bnk = 0; bnk < 4; ++bnk){
      s += acc2[bnk*256 + tid];
      q += acc2[bnk*256 + 128 + tid];
    }
    const float invM = 1.f / (float)MROWS;
    const float mean = s * invM;
    const float var  = q * invM - mean*mean;
    const float scale = g[tid] * rsqrtf(var + 1e-5f);
    ssl[2*tid + 0] = scale;
    ssl[2*tid + 1] = be[tid] - mean * scale;
  }
  __syncthreads();

  const int q = blockIdx.x * 4 + (tid >> 6);
  const int p = tid & 63;
  const float sc0 = ssl[4*p + 0], sh0 = ssl[4*p + 1];
  const float sc1 = ssl[4*p + 2], sh1 = ssl[4*p + 3];
  const float2 mxv = ((const float2*)(maxb + (size_t)q*128))[p];
  const float2 mnv = ((const float2*)(minb + (size_t)q*128))[p];
  const float h0v = (sc0 >= 0.f) ? mxv.x : mnv.x;
  const float h1v = (sc1 >= 0.f) ? mxv.y : mnv.y;
  float2 r;
  r.x = fmaxf(fmaf(sc0, h0v, sh0), 0.f);
  r.y = fmaxf(fmaf(sc1, h1v, sh1), 0.f);
  ((float2*)(out + (size_t)NB*NQ*3))[(size_t)q*64 + p] = r;
  if (p < 3){
    const int b_ = q >> 10, s = q & 1023;
    out[(size_t)q*3 + p] = xyz[((size_t)b_ * NPTS + s)*3 + p];
  }
}

// ---------- host ----------
extern "C" void kernel_launch(void* const* d_in, const int* in_sizes, int n_in,
                              void* d_out, int out_size, void* d_ws, size_t ws_size,
                              hipStream_t stream){
  (void)in_sizes; (void)n_in; (void)out_size; (void)ws_size;
  const float* xyz = (const float*)d_in[0];
  const float* pts = (const float*)d_in[1];
  const float* W0  = (const float*)d_in[2];
  const float* b0  = (const float*)d_in[3];
  const float* g0  = (const float*)d_in[4];
  const float* be0 = (const float*)d_in[5];
  const float* W1  = (const float*)d_in[6];
  const float* b1  = (const float*)d_in[7];
  const float* g1  = (const float*)d_in[8];
  const float* be1 = (const float*)d_in[9];
  const float* W2  = (const float*)d_in[10];
  const float* b2  = (const float*)d_in[11];
  const float* g2  = (const float*)d_in[12];
  const float* be2 = (const float*)d_in[13];

  // workspace: idx 2MB | acc 2048f (acc0 4x128 | acc1 4x128 | acc2 4x256) | h0 64MB | h1 64MB
  char* ws = (char*)d_ws;
  int*   idx = (int*)ws;
  float* acc = (float*)(ws + 2097152);
  unsigned* h0 = (unsigned*)(ws + 2097152 + 8192);
  unsigned* h1 = (unsigned*)(ws + 2097152 + 8192 + 67108864);
  float* maxb = (float*)h0;                    // reuses h0 (dead after l1)
  float* minb = maxb + (size_t)16384*128;
  float* out = (float*)d_out;

  float* acc0 = acc, *acc1 = acc + 512, *acc2 = acc + 1024;

  topk_kernel<<<512, 1024, 0, stream>>>(xyz, idx, acc);
  l0_mfma<<<2048, 256, 0, stream>>>(xyz, pts, idx, W0, b0, (unsigned short*)h0, acc0);
  l1_mfma<<<1024, 256, 0, stream>>>(h0, acc0, g0, be0, W1, b1, (unsigned short*)h1, acc1);
  l2_fused<<<1024, 256, 0, stream>>>(h1, acc1, g1, be1, W2, b2, maxb, minb, acc2);
  final_kernel<<<4096, 256, 0, stream>>>(xyz, maxb, minb, acc2, g2, be2, out);
}